// Round 1
// baseline (1048.018 us; speedup 1.0000x reference)
//
#include <hip/hip_runtime.h>
#include <hip/hip_bf16.h>

#define C_IN   512
#define C_OUT  256
#define HW     16384      // 128*128
#define NIMG   8
#define PTOT   (NIMG * HW)  // 131072
#define MP     1024
#define TEMP_INV (1.0f / 0.07f)
#define BN_EPS   1e-5f
#define SPB    4          // samples per block in feature kernel

typedef float  f32x4  __attribute__((ext_vector_type(4)));
typedef short  short8 __attribute__((ext_vector_type(8)));

// ---------------- K1: per-channel sums s1[c] = sum over all pixels ----------------
__global__ __launch_bounds__(256)
void ksum(const float* __restrict__ x, float* __restrict__ s1) {
    int plane = blockIdx.x;           // n*512 + c
    int c = plane & (C_IN - 1);
    const float4* p = (const float4*)(x + (size_t)plane * HW);
    float acc = 0.f;
    for (int i = threadIdx.x; i < HW / 4; i += 256) {
        float4 v = p[i];
        acc += v.x + v.y + v.z + v.w;
    }
    for (int off = 32; off; off >>= 1) acc += __shfl_down(acc, off, 64);
    __shared__ float red[4];
    int lane = threadIdx.x & 63, wv = threadIdx.x >> 6;
    if (lane == 0) red[wv] = acc;
    __syncthreads();
    if (threadIdx.x == 0)
        atomicAdd(&s1[c], red[0] + red[1] + red[2] + red[3]);
}

// ---------------- K2: gram G = X X^T via bf16 MFMA, split-K ----------------
__device__ inline short8 load_frag(const float* p) {
    float4 a = *(const float4*)p;
    float4 b = *(const float4*)(p + 4);
    union { short8 s; __hip_bfloat162 h[4]; } u;
    u.h[0] = __float22bfloat162_rn(make_float2(a.x, a.y));
    u.h[1] = __float22bfloat162_rn(make_float2(a.z, a.w));
    u.h[2] = __float22bfloat162_rn(make_float2(b.x, b.y));
    u.h[3] = __float22bfloat162_rn(make_float2(b.z, b.w));
    return u.s;
}

__global__ __launch_bounds__(256)
void kgram(const float* __restrict__ x, float* __restrict__ G) {
    // grid (4,4,32): x=tile-row, y=tile-col, z=k-chunk (4096 pixels, within one image)
    int bz  = blockIdx.z;
    int n   = bz >> 2;
    int hw0 = (bz & 3) * 4096;
    int wave = threadIdx.x >> 6;
    int lane = threadIdx.x & 63;
    int wi = wave >> 1, wj = wave & 1;
    int I0 = blockIdx.x * 128 + wi * 64;
    int J0 = blockIdx.y * 128 + wj * 64;
    int m    = lane & 15;
    int koff = (lane >> 4) * 8;

    const float* baseA[4];
    const float* baseB[4];
#pragma unroll
    for (int t = 0; t < 4; ++t) {
        baseA[t] = x + ((size_t)n * C_IN + (I0 + t * 16 + m)) * HW + hw0 + koff;
        baseB[t] = x + ((size_t)n * C_IN + (J0 + t * 16 + m)) * HW + hw0 + koff;
    }

    f32x4 acc[4][4];
#pragma unroll
    for (int i = 0; i < 4; ++i)
#pragma unroll
        for (int j = 0; j < 4; ++j) acc[i][j] = {0.f, 0.f, 0.f, 0.f};

    for (int kk = 0; kk < 4096; kk += 32) {
        short8 afr[4], bfr[4];
#pragma unroll
        for (int t = 0; t < 4; ++t) {
            afr[t] = load_frag(baseA[t] + kk);
            bfr[t] = load_frag(baseB[t] + kk);
        }
#pragma unroll
        for (int i = 0; i < 4; ++i)
#pragma unroll
            for (int j = 0; j < 4; ++j)
                acc[i][j] = __builtin_amdgcn_mfma_f32_16x16x32_bf16(
                    afr[i], bfr[j], acc[i][j], 0, 0, 0);
    }

    // C/D layout: col = lane&15, row = (lane>>4)*4 + reg  [verified mapping]
    int r0 = (lane >> 4) * 4;
    int cc = lane & 15;
#pragma unroll
    for (int i = 0; i < 4; ++i)
#pragma unroll
        for (int j = 0; j < 4; ++j)
#pragma unroll
            for (int r = 0; r < 4; ++r)
                atomicAdd(&G[(size_t)(I0 + i * 16 + r0 + r) * C_IN + (J0 + j * 16 + cc)],
                          acc[i][j][r]);
}

// ---------------- K3: BN stats + fold into conv1 weights ----------------
__global__ __launch_bounds__(256)
void kstats(const float* __restrict__ w1, const float* __restrict__ b1,
            const float* __restrict__ gamma, const float* __restrict__ beta,
            const float* __restrict__ s1, const float* __restrict__ G,
            float* __restrict__ w1p, float* __restrict__ b1p) {
    int o = blockIdx.x;
    int tid = threadIdx.x;
    __shared__ float wrow[C_IN];
    __shared__ float red[8];
    __shared__ float alpha_s;
    for (int c = tid; c < C_IN; c += 256) wrow[c] = w1[(size_t)o * C_IN + c];
    __syncthreads();

    float dot1 = 0.f, quad = 0.f;
    for (int d = tid; d < C_IN; d += 256) {
        float inner = 0.f;
        for (int c = 0; c < C_IN; ++c) inner += G[(size_t)c * C_IN + d] * wrow[c];
        quad += inner * wrow[d];
        dot1 += s1[d] * wrow[d];
    }
    for (int off = 32; off; off >>= 1) {
        dot1 += __shfl_down(dot1, off, 64);
        quad += __shfl_down(quad, off, 64);
    }
    int lane = tid & 63, wv = tid >> 6;
    if (lane == 0) { red[wv] = dot1; red[4 + wv] = quad; }
    __syncthreads();
    if (tid == 0) {
        float d1 = red[0] + red[1] + red[2] + red[3];
        float q  = red[4] + red[5] + red[6] + red[7];
        float b  = b1[o];
        float mean = d1 / (float)PTOT + b;
        float eh2  = (q + 2.f * b * d1) / (float)PTOT + b * b;
        float var  = eh2 - mean * mean;
        float al   = gamma[o] * rsqrtf(var + BN_EPS);
        alpha_s = al;
        b1p[o] = beta[o] + al * (b - mean);
    }
    __syncthreads();
    float al = alpha_s;
    for (int c = tid; c < C_IN; c += 256) w1p[(size_t)o * C_IN + c] = al * wrow[c];
}

// ---------------- K4: features at sampled pixels (conv1'+relu -> conv2 -> l2norm) ----------------
__global__ __launch_bounds__(256)
void kfeat(const float* __restrict__ x, const float* __restrict__ w1p,
           const float* __restrict__ b1p, const float* __restrict__ w2,
           const float* __restrict__ b2, const int* __restrict__ batch_idx,
           const int* __restrict__ pix_idx, float* __restrict__ cf,
           int M, int T, int n_view) {
    __shared__ float xcol[SPB][C_IN];
    __shared__ float h1[SPB][C_IN];
    __shared__ float fl[SPB][C_OUT];
    int tid = threadIdx.x;
    int m0 = blockIdx.x * SPB;

    for (int idx = tid; idx < SPB * C_IN; idx += 256) {
        int s = idx >> 9, c = idx & (C_IN - 1);
        int mm = m0 + s;
        float v = 0.f;
        if (mm < M) {
            int t = mm % T, vv = mm / T;          // cf row m = v*T + t
            int n = batch_idx[t];
            int pix = pix_idx[t * n_view + vv];
            v = x[((size_t)n * C_IN + c) * HW + pix];
        }
        xcol[s][c] = v;
    }
    __syncthreads();

    for (int o = tid; o < C_IN; o += 256) {
        float acc[SPB];
        float bb = b1p[o];
#pragma unroll
        for (int s = 0; s < SPB; ++s) acc[s] = bb;
        const float* wr = w1p + (size_t)o * C_IN;
        for (int c = 0; c < C_IN; ++c) {
            float w = wr[c];
#pragma unroll
            for (int s = 0; s < SPB; ++s) acc[s] += w * xcol[s][c];
        }
#pragma unroll
        for (int s = 0; s < SPB; ++s) h1[s][o] = fmaxf(acc[s], 0.f);
    }
    __syncthreads();

    {
        int j = tid;   // 256 threads == 256 output dims
        float acc[SPB];
        float bb = b2[j];
#pragma unroll
        for (int s = 0; s < SPB; ++s) acc[s] = bb;
        const float* wr = w2 + (size_t)j * C_IN;
        for (int o = 0; o < C_IN; ++o) {
            float w = wr[o];
#pragma unroll
            for (int s = 0; s < SPB; ++s) acc[s] += w * h1[s][o];
        }
#pragma unroll
        for (int s = 0; s < SPB; ++s) fl[s][j] = acc[s];
    }
    __syncthreads();

    // wave w normalizes sample s=w
    int wv = tid >> 6, lane = tid & 63;
    {
        float sq = 0.f;
#pragma unroll
        for (int k = 0; k < 4; ++k) { float v = fl[wv][lane + 64 * k]; sq += v * v; }
        for (int off = 32; off; off >>= 1) sq += __shfl_down(sq, off, 64);
        float nrm = __shfl(sq, 0, 64);
        float rinv = 1.f / fmaxf(sqrtf(nrm), 1e-12f);
        int mm = m0 + wv;
        if (mm < M) {
#pragma unroll
            for (int k = 0; k < 4; ++k)
                cf[(size_t)mm * C_OUT + lane + 64 * k] = fl[wv][lane + 64 * k] * rinv;
        }
    }
}

// ---------------- K5: fused logits row + contrastive loss row ----------------
__global__ __launch_bounds__(256)
void kloss(const float* __restrict__ cf, const int* __restrict__ y_cls,
           float* __restrict__ out, int M, int T) {
    int i = blockIdx.x;
    int tid = threadIdx.x;
    __shared__ float ci[C_OUT];
    __shared__ float row[MP];
    __shared__ float red[4];
    __shared__ int redi[4];
    int lane = tid & 63, wv = tid >> 6;

    ci[tid] = cf[(size_t)i * C_OUT + tid];   // C_OUT == blockDim == 256
    __syncthreads();

    int lbl_i = y_cls[i % T];

    for (int j = tid; j < M; j += 256) {
        const float* cj = cf + (size_t)j * C_OUT;
        float d = 0.f;
        for (int c = 0; c < C_OUT; c += 4) {
            float4 v = *(const float4*)(cj + c);
            d += ci[c] * v.x + ci[c + 1] * v.y + ci[c + 2] * v.z + ci[c + 3] * v.w;
        }
        row[j] = d * TEMP_INV;
    }
    __syncthreads();

    // row max (includes diagonal, as in reference)
    float mx = -1e30f;
    for (int j = tid; j < M; j += 256) mx = fmaxf(mx, row[j]);
    for (int off = 32; off; off >>= 1) mx = fmaxf(mx, __shfl_down(mx, off, 64));
    if (lane == 0) red[wv] = mx;
    __syncthreads();
    mx = fmaxf(fmaxf(red[0], red[1]), fmaxf(red[2], red[3]));
    __syncthreads();

    // negative exp sum
    float neg = 0.f;
    for (int j = tid; j < M; j += 256) {
        if (y_cls[j % T] != lbl_i) neg += expf(row[j] - mx);
    }
    for (int off = 32; off; off >>= 1) neg += __shfl_down(neg, off, 64);
    if (lane == 0) red[wv] = neg;
    __syncthreads();
    neg = red[0] + red[1] + red[2] + red[3];
    __syncthreads();

    // positive sum (diagonal excluded)
    float pos = 0.f; int cnt = 0;
    for (int j = tid; j < M; j += 256) {
        if (y_cls[j % T] == lbl_i && j != i) {
            float l = row[j] - mx;
            pos += l - logf(expf(l) + neg);
            cnt++;
        }
    }
    for (int off = 32; off; off >>= 1) {
        pos += __shfl_down(pos, off, 64);
        cnt += __shfl_down(cnt, off, 64);
    }
    if (lane == 0) { red[wv] = pos; redi[wv] = cnt; }
    __syncthreads();
    if (tid == 0) {
        float p = red[0] + red[1] + red[2] + red[3];
        int c = redi[0] + redi[1] + redi[2] + redi[3];
        float loss_i = -p / ((float)c + 1e-6f);
        atomicAdd(out, loss_i * (0.5f / (float)M));
    }
}

extern "C" void kernel_launch(void* const* d_in, const int* in_sizes, int n_in,
                              void* d_out, int out_size, void* d_ws, size_t ws_size,
                              hipStream_t stream) {
    const float* x     = (const float*)d_in[0];
    const float* w1    = (const float*)d_in[1];
    const float* b1    = (const float*)d_in[2];
    const float* gamma = (const float*)d_in[3];
    const float* beta  = (const float*)d_in[4];
    const float* w2    = (const float*)d_in[5];
    const float* b2    = (const float*)d_in[6];
    const int* batch_idx = (const int*)d_in[7];
    const int* pix_idx   = (const int*)d_in[8];
    const int* y_cls     = (const int*)d_in[9];

    int T = in_sizes[7];
    int M = in_sizes[8];
    int n_view = M / T;

    float* ws  = (float*)d_ws;
    float* s1  = ws;                       // 512
    float* G   = s1 + C_IN;                // 512*512
    float* w1p = G + C_IN * C_IN;          // 512*512
    float* b1p = w1p + C_IN * C_IN;        // 512
    float* cf  = b1p + C_IN;               // MP*C_OUT (only M rows used)

    // zero accumulators (s1 and G are contiguous) + output
    hipMemsetAsync(s1, 0, (size_t)(C_IN + C_IN * C_IN) * sizeof(float), stream);
    hipMemsetAsync(d_out, 0, sizeof(float), stream);

    ksum<<<NIMG * C_IN, 256, 0, stream>>>(x, s1);
    kgram<<<dim3(4, 4, 32), 256, 0, stream>>>(x, G);
    kstats<<<C_IN, 256, 0, stream>>>(w1, b1, gamma, beta, s1, G, w1p, b1p);
    kfeat<<<(M + SPB - 1) / SPB, 256, 0, stream>>>(x, w1p, b1p, w2, b2,
                                                   batch_idx, pix_idx, cf, M, T, n_view);
    kloss<<<M, 256, 0, stream>>>(cf, y_cls, (float*)d_out, M, T);
}

// Round 2
// 834.800 us; speedup vs baseline: 1.2554x; 1.2554x over previous
//
#include <hip/hip_runtime.h>
#include <hip/hip_bf16.h>

#define C_IN   512
#define C_OUT  256
#define HW     16384      // 128*128
#define NIMG   8
#define PTOT   (NIMG * HW)  // 131072
#define MP     1024
#define TEMP_INV (1.0f / 0.07f)
#define BN_EPS   1e-5f
#define SPB    4          // samples per block in feature kernel

typedef float  f32x4  __attribute__((ext_vector_type(4)));
typedef short  short8 __attribute__((ext_vector_type(8)));
typedef short  short4v __attribute__((ext_vector_type(4)));

// ws float layout
#define WS_S1   0
#define WS_G    (WS_S1 + C_IN)
#define WS_W1P  (WS_G + C_IN * C_IN)
#define WS_B1P  (WS_W1P + C_IN * C_IN)
#define WS_CF   (WS_B1P + C_IN)
#define WS_XB_F (WS_CF + MP * C_OUT)             // 787456 floats
#define WS_NEED_FAST ((size_t)WS_XB_F * 4 + (size_t)PTOT * C_IN * 2)

// ---------------- K0 (fast path): fused fp32->bf16 convert + channel sums ----------------
__global__ __launch_bounds__(256)
void kprep(const float* __restrict__ x, __hip_bfloat16* __restrict__ xb,
           float* __restrict__ s1) {
    int plane = blockIdx.x;           // n*512 + c
    int c = plane & (C_IN - 1);
    const float4* p = (const float4*)(x + (size_t)plane * HW);
    short4v* q = (short4v*)(xb + (size_t)plane * HW);
    float acc = 0.f;
    for (int i = threadIdx.x; i < HW / 4; i += 256) {
        float4 v = p[i];
        acc += v.x + v.y + v.z + v.w;
        union { short4v s; __hip_bfloat162 h[2]; } u;
        u.h[0] = __float22bfloat162_rn(make_float2(v.x, v.y));
        u.h[1] = __float22bfloat162_rn(make_float2(v.z, v.w));
        q[i] = u.s;
    }
    for (int off = 32; off; off >>= 1) acc += __shfl_down(acc, off, 64);
    __shared__ float red[4];
    int lane = threadIdx.x & 63, wv = threadIdx.x >> 6;
    if (lane == 0) red[wv] = acc;
    __syncthreads();
    if (threadIdx.x == 0)
        atomicAdd(&s1[c], red[0] + red[1] + red[2] + red[3]);
}

// ---------------- K1 (fallback): per-channel sums only ----------------
__global__ __launch_bounds__(256)
void ksum(const float* __restrict__ x, float* __restrict__ s1) {
    int plane = blockIdx.x;
    int c = plane & (C_IN - 1);
    const float4* p = (const float4*)(x + (size_t)plane * HW);
    float acc = 0.f;
    for (int i = threadIdx.x; i < HW / 4; i += 256) {
        float4 v = p[i];
        acc += v.x + v.y + v.z + v.w;
    }
    for (int off = 32; off; off >>= 1) acc += __shfl_down(acc, off, 64);
    __shared__ float red[4];
    int lane = threadIdx.x & 63, wv = threadIdx.x >> 6;
    if (lane == 0) red[wv] = acc;
    __syncthreads();
    if (threadIdx.x == 0)
        atomicAdd(&s1[c], red[0] + red[1] + red[2] + red[3]);
}

// ---------------- K2 (fast): gram on bf16, symmetric tiles, ping-pong prefetch ----------------
__device__ const int TILE_I[10] = {0,0,0,0,1,1,1,2,2,3};
__device__ const int TILE_J[10] = {0,1,2,3,1,2,3,2,3,3};

__global__ __launch_bounds__(256, 2)
void kgram_bf16(const __hip_bfloat16* __restrict__ xb, float* __restrict__ G) {
    int tile  = blockIdx.x;           // 0..9 upper-triangle 128x128 tiles
    int chunk = blockIdx.y;           // 0..63 : image n = chunk>>3, hw0 = (chunk&7)*2048
    int n   = chunk >> 3;
    int hw0 = (chunk & 7) * 2048;
    int wave = threadIdx.x >> 6;
    int lane = threadIdx.x & 63;
    int wi = wave >> 1, wj = wave & 1;
    int I0 = TILE_I[tile] * 128 + wi * 64;
    int J0 = TILE_J[tile] * 128 + wj * 64;
    int m    = lane & 15;
    int koff = (lane >> 4) * 8;

    const __hip_bfloat16* rowA[4];
    const __hip_bfloat16* rowB[4];
#pragma unroll
    for (int t = 0; t < 4; ++t) {
        rowA[t] = xb + ((size_t)n * C_IN + (I0 + t * 16 + m)) * HW + hw0 + koff;
        rowB[t] = xb + ((size_t)n * C_IN + (J0 + t * 16 + m)) * HW + hw0 + koff;
    }

    f32x4 acc[4][4];
#pragma unroll
    for (int i = 0; i < 4; ++i)
#pragma unroll
        for (int j = 0; j < 4; ++j) acc[i][j] = {0.f, 0.f, 0.f, 0.f};

    short8 A0[4][2], B0[4][2], A1[4][2], B1[4][2];

#define LOADSTAGE(Ab, Bb, kk)                                              \
    {                                                                      \
        _Pragma("unroll")                                                  \
        for (int t = 0; t < 4; ++t) {                                      \
            Ab[t][0] = *(const short8*)(rowA[t] + (kk));                   \
            Ab[t][1] = *(const short8*)(rowA[t] + (kk) + 32);              \
            Bb[t][0] = *(const short8*)(rowB[t] + (kk));                   \
            Bb[t][1] = *(const short8*)(rowB[t] + (kk) + 32);              \
        }                                                                  \
    }
#define MFMASTAGE(Ab, Bb)                                                  \
    {                                                                      \
        _Pragma("unroll")                                                  \
        for (int u = 0; u < 2; ++u)                                        \
            _Pragma("unroll")                                              \
            for (int i = 0; i < 4; ++i)                                    \
                _Pragma("unroll")                                          \
                for (int j = 0; j < 4; ++j)                                \
                    acc[i][j] = __builtin_amdgcn_mfma_f32_16x16x32_bf16(   \
                        Ab[i][u], Bb[j][u], acc[i][j], 0, 0, 0);           \
    }

    LOADSTAGE(A0, B0, 0)
    int kk = 0;
#pragma unroll 1
    for (int s = 0; s < 15; ++s) {
        LOADSTAGE(A1, B1, kk + 64)
        MFMASTAGE(A0, B0)
        LOADSTAGE(A0, B0, kk + 128)
        MFMASTAGE(A1, B1)
        kk += 128;
    }
    LOADSTAGE(A1, B1, kk + 64)
    MFMASTAGE(A0, B0)
    MFMASTAGE(A1, B1)
#undef LOADSTAGE
#undef MFMASTAGE

    int r0 = (lane >> 4) * 4;
    int cc = lane & 15;
#pragma unroll
    for (int i = 0; i < 4; ++i)
#pragma unroll
        for (int j = 0; j < 4; ++j)
#pragma unroll
            for (int r = 0; r < 4; ++r)
                atomicAdd(&G[(size_t)(I0 + i * 16 + r0 + r) * C_IN + (J0 + j * 16 + cc)],
                          acc[i][j][r]);
}

// ---------------- K2b: mirror upper triangle of G into lower ----------------
__global__ __launch_bounds__(256)
void kmirror(float* __restrict__ G) {
    int i = blockIdx.x;               // row
    for (int j = threadIdx.x; j < C_IN; j += 256) {
        if ((i >> 7) > (j >> 7))      // tile(i) > tile(j): not computed, copy transpose
            G[(size_t)i * C_IN + j] = G[(size_t)j * C_IN + i];
    }
}

// ---------------- K2-fallback: gram from fp32 with in-kernel cvt (round-1 version) ----------------
__device__ inline short8 load_frag_f32(const float* p) {
    float4 a = *(const float4*)p;
    float4 b = *(const float4*)(p + 4);
    union { short8 s; __hip_bfloat162 h[4]; } u;
    u.h[0] = __float22bfloat162_rn(make_float2(a.x, a.y));
    u.h[1] = __float22bfloat162_rn(make_float2(a.z, a.w));
    u.h[2] = __float22bfloat162_rn(make_float2(b.x, b.y));
    u.h[3] = __float22bfloat162_rn(make_float2(b.z, b.w));
    return u.s;
}

__global__ __launch_bounds__(256)
void kgram_f32(const float* __restrict__ x, float* __restrict__ G) {
    int bz  = blockIdx.z;
    int n   = bz >> 2;
    int hw0 = (bz & 3) * 4096;
    int wave = threadIdx.x >> 6;
    int lane = threadIdx.x & 63;
    int wi = wave >> 1, wj = wave & 1;
    int I0 = blockIdx.x * 128 + wi * 64;
    int J0 = blockIdx.y * 128 + wj * 64;
    int m    = lane & 15;
    int koff = (lane >> 4) * 8;

    const float* baseA[4];
    const float* baseB[4];
#pragma unroll
    for (int t = 0; t < 4; ++t) {
        baseA[t] = x + ((size_t)n * C_IN + (I0 + t * 16 + m)) * HW + hw0 + koff;
        baseB[t] = x + ((size_t)n * C_IN + (J0 + t * 16 + m)) * HW + hw0 + koff;
    }

    f32x4 acc[4][4];
#pragma unroll
    for (int i = 0; i < 4; ++i)
#pragma unroll
        for (int j = 0; j < 4; ++j) acc[i][j] = {0.f, 0.f, 0.f, 0.f};

    for (int kk = 0; kk < 4096; kk += 32) {
        short8 afr[4], bfr[4];
#pragma unroll
        for (int t = 0; t < 4; ++t) {
            afr[t] = load_frag_f32(baseA[t] + kk);
            bfr[t] = load_frag_f32(baseB[t] + kk);
        }
#pragma unroll
        for (int i = 0; i < 4; ++i)
#pragma unroll
            for (int j = 0; j < 4; ++j)
                acc[i][j] = __builtin_amdgcn_mfma_f32_16x16x32_bf16(
                    afr[i], bfr[j], acc[i][j], 0, 0, 0);
    }

    int r0 = (lane >> 4) * 4;
    int cc = lane & 15;
#pragma unroll
    for (int i = 0; i < 4; ++i)
#pragma unroll
        for (int j = 0; j < 4; ++j)
#pragma unroll
            for (int r = 0; r < 4; ++r)
                atomicAdd(&G[(size_t)(I0 + i * 16 + r0 + r) * C_IN + (J0 + j * 16 + cc)],
                          acc[i][j][r]);
}

// ---------------- K3: BN stats + fold into conv1 weights (row-major G dots) ----------------
__global__ __launch_bounds__(256)
void kstats(const float* __restrict__ w1, const float* __restrict__ b1,
            const float* __restrict__ gamma, const float* __restrict__ beta,
            const float* __restrict__ s1, const float* __restrict__ G,
            float* __restrict__ w1p, float* __restrict__ b1p) {
    int o = blockIdx.x;
    int tid = threadIdx.x;
    __shared__ float wrow[C_IN];
    __shared__ float red[8];
    __shared__ float alpha_s;
    for (int c = tid; c < C_IN; c += 256) wrow[c] = w1[(size_t)o * C_IN + c];
    __syncthreads();

    float dot1 = 0.f, quad = 0.f;
    // quad = sum_c wrow[c] * (G[c,:] . wrow)  — contiguous float4 reads of G rows
    for (int c = tid; c < C_IN; c += 256) {
        const float* gr = G + (size_t)c * C_IN;
        float inner = 0.f;
        for (int d = 0; d < C_IN; d += 4) {
            float4 gv = *(const float4*)(gr + d);
            float4 wv = *(const float4*)(&wrow[d]);
            inner += gv.x * wv.x + gv.y * wv.y + gv.z * wv.z + gv.w * wv.w;
        }
        quad += inner * wrow[c];
        dot1 += s1[c] * wrow[c];
    }
    for (int off = 32; off; off >>= 1) {
        dot1 += __shfl_down(dot1, off, 64);
        quad += __shfl_down(quad, off, 64);
    }
    int lane = tid & 63, wv = tid >> 6;
    if (lane == 0) { red[wv] = dot1; red[4 + wv] = quad; }
    __syncthreads();
    if (tid == 0) {
        float d1 = red[0] + red[1] + red[2] + red[3];
        float q  = red[4] + red[5] + red[6] + red[7];
        float b  = b1[o];
        float mean = d1 / (float)PTOT + b;
        float eh2  = (q + 2.f * b * d1) / (float)PTOT + b * b;
        float var  = eh2 - mean * mean;
        float al   = gamma[o] * rsqrtf(var + BN_EPS);
        alpha_s = al;
        b1p[o] = beta[o] + al * (b - mean);
    }
    __syncthreads();
    float al = alpha_s;
    for (int c = tid; c < C_IN; c += 256) w1p[(size_t)o * C_IN + c] = al * wrow[c];
}

// ---------------- K4: features at sampled pixels ----------------
__global__ __launch_bounds__(256)
void kfeat(const float* __restrict__ x, const float* __restrict__ w1p,
           const float* __restrict__ b1p, const float* __restrict__ w2,
           const float* __restrict__ b2, const int* __restrict__ batch_idx,
           const int* __restrict__ pix_idx, float* __restrict__ cf,
           int M, int T, int n_view) {
    __shared__ float xcol[SPB][C_IN];
    __shared__ float h1[SPB][C_IN];
    __shared__ float fl[SPB][C_OUT];
    int tid = threadIdx.x;
    int m0 = blockIdx.x * SPB;

    for (int idx = tid; idx < SPB * C_IN; idx += 256) {
        int s = idx >> 9, c = idx & (C_IN - 1);
        int mm = m0 + s;
        float v = 0.f;
        if (mm < M) {
            int t = mm % T, vv = mm / T;          // cf row m = v*T + t
            int n = batch_idx[t];
            int pix = pix_idx[t * n_view + vv];
            v = x[((size_t)n * C_IN + c) * HW + pix];
        }
        xcol[s][c] = v;
    }
    __syncthreads();

    for (int o = tid; o < C_IN; o += 256) {
        float acc[SPB];
        float bb = b1p[o];
#pragma unroll
        for (int s = 0; s < SPB; ++s) acc[s] = bb;
        const float* wr = w1p + (size_t)o * C_IN;
        for (int c = 0; c < C_IN; ++c) {
            float w = wr[c];
#pragma unroll
            for (int s = 0; s < SPB; ++s) acc[s] += w * xcol[s][c];
        }
#pragma unroll
        for (int s = 0; s < SPB; ++s) h1[s][o] = fmaxf(acc[s], 0.f);
    }
    __syncthreads();

    {
        int j = tid;
        float acc[SPB];
        float bb = b2[j];
#pragma unroll
        for (int s = 0; s < SPB; ++s) acc[s] = bb;
        const float* wr = w2 + (size_t)j * C_IN;
        for (int o = 0; o < C_IN; ++o) {
            float w = wr[o];
#pragma unroll
            for (int s = 0; s < SPB; ++s) acc[s] += w * h1[s][o];
        }
#pragma unroll
        for (int s = 0; s < SPB; ++s) fl[s][j] = acc[s];
    }
    __syncthreads();

    int wv = tid >> 6, lane = tid & 63;
    {
        float sq = 0.f;
#pragma unroll
        for (int k = 0; k < 4; ++k) { float v = fl[wv][lane + 64 * k]; sq += v * v; }
        for (int off = 32; off; off >>= 1) sq += __shfl_down(sq, off, 64);
        float nrm = __shfl(sq, 0, 64);
        float rinv = 1.f / fmaxf(sqrtf(nrm), 1e-12f);
        int mm = m0 + wv;
        if (mm < M) {
#pragma unroll
            for (int k = 0; k < 4; ++k)
                cf[(size_t)mm * C_OUT + lane + 64 * k] = fl[wv][lane + 64 * k] * rinv;
        }
    }
}

// ---------------- K5: fused logits row + contrastive loss row ----------------
__global__ __launch_bounds__(256)
void kloss(const float* __restrict__ cf, const int* __restrict__ y_cls,
           float* __restrict__ out, int M, int T) {
    int i = blockIdx.x;
    int tid = threadIdx.x;
    __shared__ float ci[C_OUT];
    __shared__ float row[MP];
    __shared__ float red[4];
    __shared__ int redi[4];
    int lane = tid & 63, wv = tid >> 6;

    ci[tid] = cf[(size_t)i * C_OUT + tid];
    __syncthreads();

    int lbl_i = y_cls[i % T];

    for (int j = tid; j < M; j += 256) {
        const float* cj = cf + (size_t)j * C_OUT;
        float d = 0.f;
        for (int c = 0; c < C_OUT; c += 4) {
            float4 v = *(const float4*)(cj + c);
            float4 cv = *(const float4*)(&ci[c]);
            d += cv.x * v.x + cv.y * v.y + cv.z * v.z + cv.w * v.w;
        }
        row[j] = d * TEMP_INV;
    }
    __syncthreads();

    float mx = -1e30f;
    for (int j = tid; j < M; j += 256) mx = fmaxf(mx, row[j]);
    for (int off = 32; off; off >>= 1) mx = fmaxf(mx, __shfl_down(mx, off, 64));
    if (lane == 0) red[wv] = mx;
    __syncthreads();
    mx = fmaxf(fmaxf(red[0], red[1]), fmaxf(red[2], red[3]));
    __syncthreads();

    float neg = 0.f;
    for (int j = tid; j < M; j += 256) {
        if (y_cls[j % T] != lbl_i) neg += expf(row[j] - mx);
    }
    for (int off = 32; off; off >>= 1) neg += __shfl_down(neg, off, 64);
    if (lane == 0) red[wv] = neg;
    __syncthreads();
    neg = red[0] + red[1] + red[2] + red[3];
    __syncthreads();

    float pos = 0.f; int cnt = 0;
    for (int j = tid; j < M; j += 256) {
        if (y_cls[j % T] == lbl_i && j != i) {
            float l = row[j] - mx;
            pos += l - logf(expf(l) + neg);
            cnt++;
        }
    }
    for (int off = 32; off; off >>= 1) {
        pos += __shfl_down(pos, off, 64);
        cnt += __shfl_down(cnt, off, 64);
    }
    if (lane == 0) { red[wv] = pos; redi[wv] = cnt; }
    __syncthreads();
    if (tid == 0) {
        float p = red[0] + red[1] + red[2] + red[3];
        int c = redi[0] + redi[1] + redi[2] + redi[3];
        float loss_i = -p / ((float)c + 1e-6f);
        atomicAdd(out, loss_i * (0.5f / (float)M));
    }
}

extern "C" void kernel_launch(void* const* d_in, const int* in_sizes, int n_in,
                              void* d_out, int out_size, void* d_ws, size_t ws_size,
                              hipStream_t stream) {
    const float* x     = (const float*)d_in[0];
    const float* w1    = (const float*)d_in[1];
    const float* b1    = (const float*)d_in[2];
    const float* gamma = (const float*)d_in[3];
    const float* beta  = (const float*)d_in[4];
    const float* w2    = (const float*)d_in[5];
    const float* b2    = (const float*)d_in[6];
    const int* batch_idx = (const int*)d_in[7];
    const int* pix_idx   = (const int*)d_in[8];
    const int* y_cls     = (const int*)d_in[9];

    int T = in_sizes[7];
    int M = in_sizes[8];
    int n_view = M / T;

    float* ws  = (float*)d_ws;
    float* s1  = ws + WS_S1;
    float* G   = ws + WS_G;
    float* w1p = ws + WS_W1P;
    float* b1p = ws + WS_B1P;
    float* cf  = ws + WS_CF;
    __hip_bfloat16* xb = (__hip_bfloat16*)(ws + WS_XB_F);

    // zero accumulators (s1 and G are contiguous) + output
    hipMemsetAsync(s1, 0, (size_t)(C_IN + C_IN * C_IN) * sizeof(float), stream);
    hipMemsetAsync(d_out, 0, sizeof(float), stream);

    if (ws_size >= WS_NEED_FAST) {
        kprep<<<NIMG * C_IN, 256, 0, stream>>>(x, xb, s1);
        kgram_bf16<<<dim3(10, 64), 256, 0, stream>>>(xb, G);
        kmirror<<<C_IN, 256, 0, stream>>>(G);
    } else {
        ksum<<<NIMG * C_IN, 256, 0, stream>>>(x, s1);
        kgram_f32<<<dim3(4, 4, 32), 256, 0, stream>>>(x, G);
    }
    kstats<<<C_IN, 256, 0, stream>>>(w1, b1, gamma, beta, s1, G, w1p, b1p);
    kfeat<<<(M + SPB - 1) / SPB, 256, 0, stream>>>(x, w1p, b1p, w2, b2,
                                                   batch_idx, pix_idx, cf, M, T, n_view);
    kloss<<<M, 256, 0, stream>>>(cf, y_cls, (float*)d_out, M, T);
}

// Round 3
// 769.947 us; speedup vs baseline: 1.3612x; 1.0842x over previous
//
#include <hip/hip_runtime.h>
#include <hip/hip_bf16.h>

#define C_IN   512
#define C_OUT  256
#define HW     16384      // 128*128
#define NIMG   8
#define PTOT   (NIMG * HW)  // 131072
#define MP     1024
#define TEMP_INV (1.0f / 0.07f)
#define BN_EPS   1e-5f
#define SPB    4          // samples per block in feature kernel
#define OGRP   8          // outputs per block in kstats
#define IGRP   4          // anchor rows per block in kloss

typedef float  f32x4  __attribute__((ext_vector_type(4)));
typedef short  short8 __attribute__((ext_vector_type(8)));
typedef short  short4v __attribute__((ext_vector_type(4)));

// ws float layout
#define WS_S1   0
#define WS_G    (WS_S1 + C_IN)
#define WS_W1P  (WS_G + C_IN * C_IN)
#define WS_B1P  (WS_W1P + C_IN * C_IN)
#define WS_CF   (WS_B1P + C_IN)
#define WS_XB_F (WS_CF + MP * C_OUT)             // 787456 floats
#define WS_NEED_FAST ((size_t)WS_XB_F * 4 + (size_t)PTOT * C_IN * 2)

// ---------------- K0 (fast path): fused fp32->bf16 convert + channel sums ----------------
__global__ __launch_bounds__(256)
void kprep(const float* __restrict__ x, __hip_bfloat16* __restrict__ xb,
           float* __restrict__ s1) {
    int plane = blockIdx.x;           // n*512 + c
    int c = plane & (C_IN - 1);
    const float4* p = (const float4*)(x + (size_t)plane * HW);
    short4v* q = (short4v*)(xb + (size_t)plane * HW);
    float acc = 0.f;
    for (int i = threadIdx.x; i < HW / 4; i += 256) {
        float4 v = p[i];
        acc += v.x + v.y + v.z + v.w;
        union { short4v s; __hip_bfloat162 h[2]; } u;
        u.h[0] = __float22bfloat162_rn(make_float2(v.x, v.y));
        u.h[1] = __float22bfloat162_rn(make_float2(v.z, v.w));
        q[i] = u.s;
    }
    for (int off = 32; off; off >>= 1) acc += __shfl_down(acc, off, 64);
    __shared__ float red[4];
    int lane = threadIdx.x & 63, wv = threadIdx.x >> 6;
    if (lane == 0) red[wv] = acc;
    __syncthreads();
    if (threadIdx.x == 0)
        atomicAdd(&s1[c], red[0] + red[1] + red[2] + red[3]);
}

// ---------------- K1 (fallback): per-channel sums only ----------------
__global__ __launch_bounds__(256)
void ksum(const float* __restrict__ x, float* __restrict__ s1) {
    int plane = blockIdx.x;
    int c = plane & (C_IN - 1);
    const float4* p = (const float4*)(x + (size_t)plane * HW);
    float acc = 0.f;
    for (int i = threadIdx.x; i < HW / 4; i += 256) {
        float4 v = p[i];
        acc += v.x + v.y + v.z + v.w;
    }
    for (int off = 32; off; off >>= 1) acc += __shfl_down(acc, off, 64);
    __shared__ float red[4];
    int lane = threadIdx.x & 63, wv = threadIdx.x >> 6;
    if (lane == 0) red[wv] = acc;
    __syncthreads();
    if (threadIdx.x == 0)
        atomicAdd(&s1[c], red[0] + red[1] + red[2] + red[3]);
}

// ---------------- K2 (fast): gram on bf16, symmetric tiles, ping-pong prefetch ----------------
// chunk = 1024 pixels -> grid (10 tiles, 128 chunks) = 1280 blocks = 5 blocks/CU
__device__ const int TILE_I[10] = {0,0,0,0,1,1,1,2,2,3};
__device__ const int TILE_J[10] = {0,1,2,3,1,2,3,2,3,3};

__global__ __launch_bounds__(256, 2)
void kgram_bf16(const __hip_bfloat16* __restrict__ xb, float* __restrict__ G) {
    int tile  = blockIdx.x;           // 0..9 upper-triangle 128x128 tiles
    int chunk = blockIdx.y;           // 0..127 : image n = chunk>>4, hw0 = (chunk&15)*1024
    int n   = chunk >> 4;
    int hw0 = (chunk & 15) * 1024;
    int wave = threadIdx.x >> 6;
    int lane = threadIdx.x & 63;
    int wi = wave >> 1, wj = wave & 1;
    int I0 = TILE_I[tile] * 128 + wi * 64;
    int J0 = TILE_J[tile] * 128 + wj * 64;
    int m    = lane & 15;
    int koff = (lane >> 4) * 8;

    const __hip_bfloat16* rowA[4];
    const __hip_bfloat16* rowB[4];
#pragma unroll
    for (int t = 0; t < 4; ++t) {
        rowA[t] = xb + ((size_t)n * C_IN + (I0 + t * 16 + m)) * HW + hw0 + koff;
        rowB[t] = xb + ((size_t)n * C_IN + (J0 + t * 16 + m)) * HW + hw0 + koff;
    }

    f32x4 acc[4][4];
#pragma unroll
    for (int i = 0; i < 4; ++i)
#pragma unroll
        for (int j = 0; j < 4; ++j) acc[i][j] = {0.f, 0.f, 0.f, 0.f};

    short8 A0[4][2], B0[4][2], A1[4][2], B1[4][2];

#define LOADSTAGE(Ab, Bb, kk)                                              \
    {                                                                      \
        _Pragma("unroll")                                                  \
        for (int t = 0; t < 4; ++t) {                                      \
            Ab[t][0] = *(const short8*)(rowA[t] + (kk));                   \
            Ab[t][1] = *(const short8*)(rowA[t] + (kk) + 32);              \
            Bb[t][0] = *(const short8*)(rowB[t] + (kk));                   \
            Bb[t][1] = *(const short8*)(rowB[t] + (kk) + 32);              \
        }                                                                  \
    }
#define MFMASTAGE(Ab, Bb)                                                  \
    {                                                                      \
        _Pragma("unroll")                                                  \
        for (int u = 0; u < 2; ++u)                                        \
            _Pragma("unroll")                                              \
            for (int i = 0; i < 4; ++i)                                    \
                _Pragma("unroll")                                          \
                for (int j = 0; j < 4; ++j)                                \
                    acc[i][j] = __builtin_amdgcn_mfma_f32_16x16x32_bf16(   \
                        Ab[i][u], Bb[j][u], acc[i][j], 0, 0, 0);           \
    }

    LOADSTAGE(A0, B0, 0)
    int kk = 0;
#pragma unroll 1
    for (int s = 0; s < 7; ++s) {          // 16 stages of K=64 total
        LOADSTAGE(A1, B1, kk + 64)
        MFMASTAGE(A0, B0)
        LOADSTAGE(A0, B0, kk + 128)
        MFMASTAGE(A1, B1)
        kk += 128;
    }
    LOADSTAGE(A1, B1, kk + 64)
    MFMASTAGE(A0, B0)
    MFMASTAGE(A1, B1)
#undef LOADSTAGE
#undef MFMASTAGE

    int r0 = (lane >> 4) * 4;
    int cc = lane & 15;
#pragma unroll
    for (int i = 0; i < 4; ++i)
#pragma unroll
        for (int j = 0; j < 4; ++j)
#pragma unroll
            for (int r = 0; r < 4; ++r)
                atomicAdd(&G[(size_t)(I0 + i * 16 + r0 + r) * C_IN + (J0 + j * 16 + cc)],
                          acc[i][j][r]);
}

// ---------------- K2b: mirror upper triangle of G into lower ----------------
__global__ __launch_bounds__(256)
void kmirror(float* __restrict__ G) {
    int i = blockIdx.x;               // row
    for (int j = threadIdx.x; j < C_IN; j += 256) {
        if ((i >> 7) > (j >> 7))      // tile(i) > tile(j): not computed, copy transpose
            G[(size_t)i * C_IN + j] = G[(size_t)j * C_IN + i];
    }
}

// ---------------- K2-fallback: gram from fp32 with in-kernel cvt ----------------
__device__ inline short8 load_frag_f32(const float* p) {
    float4 a = *(const float4*)p;
    float4 b = *(const float4*)(p + 4);
    union { short8 s; __hip_bfloat162 h[4]; } u;
    u.h[0] = __float22bfloat162_rn(make_float2(a.x, a.y));
    u.h[1] = __float22bfloat162_rn(make_float2(a.z, a.w));
    u.h[2] = __float22bfloat162_rn(make_float2(b.x, b.y));
    u.h[3] = __float22bfloat162_rn(make_float2(b.z, b.w));
    return u.s;
}

__global__ __launch_bounds__(256)
void kgram_f32(const float* __restrict__ x, float* __restrict__ G) {
    int bz  = blockIdx.z;
    int n   = bz >> 2;
    int hw0 = (bz & 3) * 4096;
    int wave = threadIdx.x >> 6;
    int lane = threadIdx.x & 63;
    int wi = wave >> 1, wj = wave & 1;
    int I0 = blockIdx.x * 128 + wi * 64;
    int J0 = blockIdx.y * 128 + wj * 64;
    int m    = lane & 15;
    int koff = (lane >> 4) * 8;

    const float* baseA[4];
    const float* baseB[4];
#pragma unroll
    for (int t = 0; t < 4; ++t) {
        baseA[t] = x + ((size_t)n * C_IN + (I0 + t * 16 + m)) * HW + hw0 + koff;
        baseB[t] = x + ((size_t)n * C_IN + (J0 + t * 16 + m)) * HW + hw0 + koff;
    }

    f32x4 acc[4][4];
#pragma unroll
    for (int i = 0; i < 4; ++i)
#pragma unroll
        for (int j = 0; j < 4; ++j) acc[i][j] = {0.f, 0.f, 0.f, 0.f};

    for (int kk = 0; kk < 4096; kk += 32) {
        short8 afr[4], bfr[4];
#pragma unroll
        for (int t = 0; t < 4; ++t) {
            afr[t] = load_frag_f32(baseA[t] + kk);
            bfr[t] = load_frag_f32(baseB[t] + kk);
        }
#pragma unroll
        for (int i = 0; i < 4; ++i)
#pragma unroll
            for (int j = 0; j < 4; ++j)
                acc[i][j] = __builtin_amdgcn_mfma_f32_16x16x32_bf16(
                    afr[i], bfr[j], acc[i][j], 0, 0, 0);
    }

    int r0 = (lane >> 4) * 4;
    int cc = lane & 15;
#pragma unroll
    for (int i = 0; i < 4; ++i)
#pragma unroll
        for (int j = 0; j < 4; ++j)
#pragma unroll
            for (int r = 0; r < 4; ++r)
                atomicAdd(&G[(size_t)(I0 + i * 16 + r0 + r) * C_IN + (J0 + j * 16 + cc)],
                          acc[i][j][r]);
}

// ---------------- K3: BN stats + fold, 8 outputs per block ----------------
__global__ __launch_bounds__(256)
void kstats(const float* __restrict__ w1, const float* __restrict__ b1,
            const float* __restrict__ gamma, const float* __restrict__ beta,
            const float* __restrict__ s1, const float* __restrict__ G,
            float* __restrict__ w1p, float* __restrict__ b1p) {
    int o0 = blockIdx.x * OGRP;
    int tid = threadIdx.x;
    __shared__ float wr[OGRP][C_IN];          // 16 KB
    __shared__ float redd[4][OGRP];
    __shared__ float redq[4][OGRP];
    __shared__ float alpha_s[OGRP];

    for (int idx = tid; idx < OGRP * C_IN; idx += 256) {
        int og = idx >> 9, c = idx & (C_IN - 1);
        wr[og][c] = w1[(size_t)(o0 + og) * C_IN + c];
    }
    __syncthreads();

    float dot1[OGRP], quad[OGRP];
#pragma unroll
    for (int og = 0; og < OGRP; ++og) { dot1[og] = 0.f; quad[og] = 0.f; }

    for (int c = tid; c < C_IN; c += 256) {
        const float* gr = G + (size_t)c * C_IN;
        float s1c = s1[c];
        float inner[OGRP];
#pragma unroll
        for (int og = 0; og < OGRP; ++og) inner[og] = 0.f;
        for (int d = 0; d < C_IN; d += 4) {
            float4 gv = *(const float4*)(gr + d);
#pragma unroll
            for (int og = 0; og < OGRP; ++og) {
                float4 wv = *(const float4*)(&wr[og][d]);
                inner[og] += gv.x * wv.x + gv.y * wv.y + gv.z * wv.z + gv.w * wv.w;
            }
        }
#pragma unroll
        for (int og = 0; og < OGRP; ++og) {
            float wc = wr[og][c];
            quad[og] += inner[og] * wc;
            dot1[og] += s1c * wc;
        }
    }
#pragma unroll
    for (int og = 0; og < OGRP; ++og) {
        for (int off = 32; off; off >>= 1) {
            dot1[og] += __shfl_down(dot1[og], off, 64);
            quad[og] += __shfl_down(quad[og], off, 64);
        }
    }
    int lane = tid & 63, wv = tid >> 6;
    if (lane == 0) {
#pragma unroll
        for (int og = 0; og < OGRP; ++og) { redd[wv][og] = dot1[og]; redq[wv][og] = quad[og]; }
    }
    __syncthreads();
    if (tid < OGRP) {
        int og = tid;
        float d1 = redd[0][og] + redd[1][og] + redd[2][og] + redd[3][og];
        float q  = redq[0][og] + redq[1][og] + redq[2][og] + redq[3][og];
        float b  = b1[o0 + og];
        float mean = d1 / (float)PTOT + b;
        float eh2  = (q + 2.f * b * d1) / (float)PTOT + b * b;
        float var  = eh2 - mean * mean;
        float al   = gamma[o0 + og] * rsqrtf(var + BN_EPS);
        alpha_s[og] = al;
        b1p[o0 + og] = beta[o0 + og] + al * (b - mean);
    }
    __syncthreads();
    for (int idx = tid; idx < OGRP * C_IN; idx += 256) {
        int og = idx >> 9, c = idx & (C_IN - 1);
        w1p[(size_t)(o0 + og) * C_IN + c] = alpha_s[og] * wr[og][c];
    }
}

// ---------------- K4: features at sampled pixels ----------------
__global__ __launch_bounds__(256)
void kfeat(const float* __restrict__ x, const float* __restrict__ w1p,
           const float* __restrict__ b1p, const float* __restrict__ w2,
           const float* __restrict__ b2, const int* __restrict__ batch_idx,
           const int* __restrict__ pix_idx, float* __restrict__ cf,
           int M, int T, int n_view) {
    __shared__ float xcol[SPB][C_IN];
    __shared__ float h1[SPB][C_IN];
    __shared__ float fl[SPB][C_OUT];
    int tid = threadIdx.x;
    int m0 = blockIdx.x * SPB;

    for (int idx = tid; idx < SPB * C_IN; idx += 256) {
        int s = idx >> 9, c = idx & (C_IN - 1);
        int mm = m0 + s;
        float v = 0.f;
        if (mm < M) {
            int t = mm % T, vv = mm / T;          // cf row m = v*T + t
            int n = batch_idx[t];
            int pix = pix_idx[t * n_view + vv];
            v = x[((size_t)n * C_IN + c) * HW + pix];
        }
        xcol[s][c] = v;
    }
    __syncthreads();

    for (int o = tid; o < C_IN; o += 256) {
        float acc[SPB];
        float bb = b1p[o];
#pragma unroll
        for (int s = 0; s < SPB; ++s) acc[s] = bb;
        const float* wrp = w1p + (size_t)o * C_IN;
        for (int c = 0; c < C_IN; ++c) {
            float w = wrp[c];
#pragma unroll
            for (int s = 0; s < SPB; ++s) acc[s] += w * xcol[s][c];
        }
#pragma unroll
        for (int s = 0; s < SPB; ++s) h1[s][o] = fmaxf(acc[s], 0.f);
    }
    __syncthreads();

    {
        int j = tid;
        float acc[SPB];
        float bb = b2[j];
#pragma unroll
        for (int s = 0; s < SPB; ++s) acc[s] = bb;
        const float* wrp = w2 + (size_t)j * C_IN;
        for (int o = 0; o < C_IN; ++o) {
            float w = wrp[o];
#pragma unroll
            for (int s = 0; s < SPB; ++s) acc[s] += w * h1[s][o];
        }
#pragma unroll
        for (int s = 0; s < SPB; ++s) fl[s][j] = acc[s];
    }
    __syncthreads();

    int wv = tid >> 6, lane = tid & 63;
    {
        float sq = 0.f;
#pragma unroll
        for (int k = 0; k < 4; ++k) { float v = fl[wv][lane + 64 * k]; sq += v * v; }
        for (int off = 32; off; off >>= 1) sq += __shfl_down(sq, off, 64);
        float nrm = __shfl(sq, 0, 64);
        float rinv = 1.f / fmaxf(sqrtf(nrm), 1e-12f);
        int mm = m0 + wv;
        if (mm < M) {
#pragma unroll
            for (int k = 0; k < 4; ++k)
                cf[(size_t)mm * C_OUT + lane + 64 * k] = fl[wv][lane + 64 * k] * rinv;
        }
    }
}

// ---------------- K5: fused logits + loss, 4 anchor rows per block ----------------
__global__ __launch_bounds__(256)
void kloss(const float* __restrict__ cf, const int* __restrict__ y_cls,
           float* __restrict__ out, int M, int T) {
    int i0 = blockIdx.x * IGRP;
    int tid = threadIdx.x;
    __shared__ float ci[IGRP][C_OUT];         // 4 KB
    __shared__ float row[IGRP][MP];           // 16 KB
    __shared__ int   lbl[MP];                 // 4 KB
    __shared__ float redl[IGRP];
    int lane = tid & 63, wv = tid >> 6;

    for (int idx = tid; idx < IGRP * C_OUT; idx += 256) {
        int g = idx >> 8, c = idx & (C_OUT - 1);
        int ii = i0 + g;
        ci[g][c] = (ii < M) ? cf[(size_t)ii * C_OUT + c] : 0.f;
    }
    for (int j = tid; j < M; j += 256) lbl[j] = y_cls[j % T];
    __syncthreads();

    for (int j = tid; j < M; j += 256) {
        const float* cj = cf + (size_t)j * C_OUT;
        float acc[IGRP];
#pragma unroll
        for (int g = 0; g < IGRP; ++g) acc[g] = 0.f;
        for (int c = 0; c < C_OUT; c += 4) {
            float4 v = *(const float4*)(cj + c);
#pragma unroll
            for (int g = 0; g < IGRP; ++g) {
                float4 cv = *(const float4*)(&ci[g][c]);
                acc[g] += cv.x * v.x + cv.y * v.y + cv.z * v.z + cv.w * v.w;
            }
        }
#pragma unroll
        for (int g = 0; g < IGRP; ++g) row[g][j] = acc[g] * TEMP_INV;
    }
    __syncthreads();

    // wave wv handles anchor i = i0 + wv
    int i = i0 + wv;
    if (i < M) {
        int lbl_i = lbl[i];
        const float* r = row[wv];

        float mx = -1e30f;
        for (int j = lane; j < M; j += 64) mx = fmaxf(mx, r[j]);
        for (int off = 32; off; off >>= 1) mx = fmaxf(mx, __shfl_down(mx, off, 64));
        mx = __shfl(mx, 0, 64);

        float neg = 0.f;
        for (int j = lane; j < M; j += 64)
            if (lbl[j] != lbl_i) neg += expf(r[j] - mx);
        for (int off = 32; off; off >>= 1) neg += __shfl_down(neg, off, 64);
        neg = __shfl(neg, 0, 64);

        float pos = 0.f; int cnt = 0;
        for (int j = lane; j < M; j += 64) {
            if (lbl[j] == lbl_i && j != i) {
                float l = r[j] - mx;
                pos += l - logf(expf(l) + neg);
                cnt++;
            }
        }
        for (int off = 32; off; off >>= 1) {
            pos += __shfl_down(pos, off, 64);
            cnt += __shfl_down(cnt, off, 64);
        }
        if (lane == 0) redl[wv] = -pos / ((float)cnt + 1e-6f);
    } else if (lane == 0) redl[wv] = 0.f;
    __syncthreads();
    if (tid == 0) {
        float s = redl[0] + redl[1] + redl[2] + redl[3];
        atomicAdd(out, s * (0.5f / (float)M));
    }
}

extern "C" void kernel_launch(void* const* d_in, const int* in_sizes, int n_in,
                              void* d_out, int out_size, void* d_ws, size_t ws_size,
                              hipStream_t stream) {
    const float* x     = (const float*)d_in[0];
    const float* w1    = (const float*)d_in[1];
    const float* b1    = (const float*)d_in[2];
    const float* gamma = (const float*)d_in[3];
    const float* beta  = (const float*)d_in[4];
    const float* w2    = (const float*)d_in[5];
    const float* b2    = (const float*)d_in[6];
    const int* batch_idx = (const int*)d_in[7];
    const int* pix_idx   = (const int*)d_in[8];
    const int* y_cls     = (const int*)d_in[9];

    int T = in_sizes[7];
    int M = in_sizes[8];
    int n_view = M / T;

    float* ws  = (float*)d_ws;
    float* s1  = ws + WS_S1;
    float* G   = ws + WS_G;
    float* w1p = ws + WS_W1P;
    float* b1p = ws + WS_B1P;
    float* cf  = ws + WS_CF;
    __hip_bfloat16* xb = (__hip_bfloat16*)(ws + WS_XB_F);

    hipMemsetAsync(s1, 0, (size_t)(C_IN + C_IN * C_IN) * sizeof(float), stream);
    hipMemsetAsync(d_out, 0, sizeof(float), stream);

    if (ws_size >= WS_NEED_FAST) {
        kprep<<<NIMG * C_IN, 256, 0, stream>>>(x, xb, s1);
        kgram_bf16<<<dim3(10, 128), 256, 0, stream>>>(xb, G);
        kmirror<<<C_IN, 256, 0, stream>>>(G);
    } else {
        ksum<<<NIMG * C_IN, 256, 0, stream>>>(x, s1);
        kgram_f32<<<dim3(4, 4, 32), 256, 0, stream>>>(x, G);
    }
    kstats<<<C_IN / OGRP, 256, 0, stream>>>(w1, b1, gamma, beta, s1, G, w1p, b1p);
    kfeat<<<(M + SPB - 1) / SPB, 256, 0, stream>>>(x, w1p, b1p, w2, b2,
                                                   batch_idx, pix_idx, cf, M, T, n_view);
    kloss<<<(M + IGRP - 1) / IGRP, 256, 0, stream>>>(cf, y_cls, (float*)d_out, M, T);
}

// Round 4
// 706.192 us; speedup vs baseline: 1.4840x; 1.0903x over previous
//
#include <hip/hip_runtime.h>
#include <hip/hip_bf16.h>

#define C_IN   512
#define C_OUT  256
#define HW     16384      // 128*128
#define NIMG   8
#define PTOT   (NIMG * HW)  // 131072
#define MP     1024
#define TEMP_INV (1.0f / 0.07f)
#define BN_EPS   1e-5f
#define SPB    4          // samples per block in feature kernel
#define OGRP   8          // outputs per block in kstats
#define IGRP   8          // anchor rows per block in kloss
#define BK     64         // K-chunk per LDS stage in kgram

typedef float  f32x4  __attribute__((ext_vector_type(4)));
typedef short  short8 __attribute__((ext_vector_type(8)));
typedef short  short4v __attribute__((ext_vector_type(4)));

// ws float layout
#define WS_S1   0
#define WS_G    (WS_S1 + C_IN)
#define WS_W1P  (WS_G + C_IN * C_IN)
#define WS_B1P  (WS_W1P + C_IN * C_IN)
#define WS_CF   (WS_B1P + C_IN)
#define WS_XB_F (WS_CF + MP * C_OUT)             // 787456 floats
#define WS_NEED_FAST ((size_t)WS_XB_F * 4 + (size_t)PTOT * C_IN * 2)

// ---------------- K0 (fast path): fused fp32->bf16 convert + channel sums ----------------
__global__ __launch_bounds__(256)
void kprep(const float* __restrict__ x, __hip_bfloat16* __restrict__ xb,
           float* __restrict__ s1) {
    int plane = blockIdx.x;           // n*512 + c
    int c = plane & (C_IN - 1);
    const float4* p = (const float4*)(x + (size_t)plane * HW);
    short4v* q = (short4v*)(xb + (size_t)plane * HW);
    float acc = 0.f;
    for (int i = threadIdx.x; i < HW / 4; i += 256) {
        float4 v = p[i];
        acc += v.x + v.y + v.z + v.w;
        union { short4v s; __hip_bfloat162 h[2]; } u;
        u.h[0] = __float22bfloat162_rn(make_float2(v.x, v.y));
        u.h[1] = __float22bfloat162_rn(make_float2(v.z, v.w));
        q[i] = u.s;
    }
    for (int off = 32; off; off >>= 1) acc += __shfl_down(acc, off, 64);
    __shared__ float red[4];
    int lane = threadIdx.x & 63, wv = threadIdx.x >> 6;
    if (lane == 0) red[wv] = acc;
    __syncthreads();
    if (threadIdx.x == 0)
        atomicAdd(&s1[c], red[0] + red[1] + red[2] + red[3]);
}

// ---------------- K1 (fallback): per-channel sums only ----------------
__global__ __launch_bounds__(256)
void ksum(const float* __restrict__ x, float* __restrict__ s1) {
    int plane = blockIdx.x;
    int c = plane & (C_IN - 1);
    const float4* p = (const float4*)(x + (size_t)plane * HW);
    float acc = 0.f;
    for (int i = threadIdx.x; i < HW / 4; i += 256) {
        float4 v = p[i];
        acc += v.x + v.y + v.z + v.w;
    }
    for (int off = 32; off; off >>= 1) acc += __shfl_down(acc, off, 64);
    __shared__ float red[4];
    int lane = threadIdx.x & 63, wv = threadIdx.x >> 6;
    if (lane == 0) red[wv] = acc;
    __syncthreads();
    if (threadIdx.x == 0)
        atomicAdd(&s1[c], red[0] + red[1] + red[2] + red[3]);
}

// ---------------- K2 (fast): LDS-staged gram, global_load_lds + XOR swizzle ----------------
// grid (10 tiles, 128 chunks); chunk = 1024 pixels within one image.
// LDS layout per panel: [row 0..127][slot 0..7], slot s of row r holds global
// k-quad (s ^ (r&7)) (8 bf16 = 16 B). Staged with global_load_lds width 16:
// per instruction, lane l writes LDS base + l*16 => row l>>3 (8 rows), slot l&7;
// lane reads global quad (l&7)^(row&7) => each row's 128 B fetched contiguously.
__device__ const int TILE_I[10] = {0,0,0,0,1,1,1,2,2,3};
__device__ const int TILE_J[10] = {0,1,2,3,1,2,3,2,3,3};

__global__ __launch_bounds__(256, 2)
void kgram_bf16(const __hip_bfloat16* __restrict__ xb, float* __restrict__ G) {
    __shared__ __hip_bfloat16 Abuf[2][128 * BK];   // 16 KB each
    __shared__ __hip_bfloat16 Bbuf[2][128 * BK];
    int tile  = blockIdx.x;
    int chunk = blockIdx.y;           // image n = chunk>>4, hw0 = (chunk&15)*1024
    int n   = chunk >> 4;
    int hw0 = (chunk & 15) * 1024;
    int wave = threadIdx.x >> 6;
    int lane = threadIdx.x & 63;
    int wi = wave >> 1, wj = wave & 1;
    int IT = TILE_I[tile] * 128;
    int JT = TILE_J[tile] * 128;

    const __hip_bfloat16* gA = xb + ((size_t)n * C_IN + IT) * HW + hw0;
    const __hip_bfloat16* gB = xb + ((size_t)n * C_IN + JT) * HW + hw0;

    int rrel = lane >> 3;             // 0..7
    int slot = lane & 7;

    f32x4 acc[4][4];
#pragma unroll
    for (int i = 0; i < 4; ++i)
#pragma unroll
        for (int j = 0; j < 4; ++j) acc[i][j] = {0.f, 0.f, 0.f, 0.f};

    int m  = lane & 15;
    int kq = lane >> 4;               // 0..3

#define STAGE(s, pb)                                                          \
    {                                                                         \
        int kk_ = (s) * BK;                                                   \
        _Pragma("unroll")                                                     \
        for (int i_ = 0; i_ < 4; ++i_) {                                      \
            int row_ = wave * 32 + i_ * 8 + rrel;                             \
            int g_   = slot ^ (row_ & 7);                                     \
            __builtin_amdgcn_global_load_lds(                                 \
                (const __attribute__((address_space(1))) void*)               \
                    (gA + (size_t)row_ * HW + kk_ + g_ * 8),                  \
                (__attribute__((address_space(3))) void*)                     \
                    (&Abuf[pb][(wave * 32 + i_ * 8) * BK]),                   \
                16, 0, 0);                                                    \
            __builtin_amdgcn_global_load_lds(                                 \
                (const __attribute__((address_space(1))) void*)               \
                    (gB + (size_t)row_ * HW + kk_ + g_ * 8),                  \
                (__attribute__((address_space(3))) void*)                     \
                    (&Bbuf[pb][(wave * 32 + i_ * 8) * BK]),                   \
                16, 0, 0);                                                    \
        }                                                                     \
    }

#define COMPUTE(pb)                                                           \
    {                                                                         \
        _Pragma("unroll")                                                     \
        for (int h_ = 0; h_ < 2; ++h_) {                                      \
            short8 af_[4], bf_[4];                                            \
            _Pragma("unroll")                                                 \
            for (int t_ = 0; t_ < 4; ++t_) {                                  \
                int ra_ = wi * 64 + t_ * 16 + m;                              \
                int qa_ = (h_ * 4 + kq) ^ (ra_ & 7);                          \
                af_[t_] = *(const short8*)&Abuf[pb][ra_ * BK + qa_ * 8];      \
                int rb_ = wj * 64 + t_ * 16 + m;                              \
                int qb_ = (h_ * 4 + kq) ^ (rb_ & 7);                          \
                bf_[t_] = *(const short8*)&Bbuf[pb][rb_ * BK + qb_ * 8];      \
            }                                                                 \
            _Pragma("unroll")                                                 \
            for (int i_ = 0; i_ < 4; ++i_)                                    \
                _Pragma("unroll")                                             \
                for (int j_ = 0; j_ < 4; ++j_)                                \
                    acc[i_][j_] = __builtin_amdgcn_mfma_f32_16x16x32_bf16(    \
                        af_[i_], bf_[j_], acc[i_][j_], 0, 0, 0);              \
        }                                                                     \
    }

    STAGE(0, 0)
    __syncthreads();
    int pb = 0;
#pragma unroll 1
    for (int s = 0; s < 16; ++s) {
        if (s < 15) STAGE(s + 1, pb ^ 1)
        COMPUTE(pb)
        __syncthreads();
        pb ^= 1;
    }
#undef STAGE
#undef COMPUTE

    int r0 = (lane >> 4) * 4;
    int cc = lane & 15;
#pragma unroll
    for (int i = 0; i < 4; ++i)
#pragma unroll
        for (int j = 0; j < 4; ++j)
#pragma unroll
            for (int r = 0; r < 4; ++r)
                atomicAdd(&G[(size_t)(IT + wi * 64 + i * 16 + r0 + r) * C_IN
                             + (JT + wj * 64 + j * 16 + cc)],
                          acc[i][j][r]);
}

// ---------------- K2b: mirror upper triangle of G into lower ----------------
__global__ __launch_bounds__(256)
void kmirror(float* __restrict__ G) {
    int i = blockIdx.x;               // row
    for (int j = threadIdx.x; j < C_IN; j += 256) {
        if ((i >> 7) > (j >> 7))
            G[(size_t)i * C_IN + j] = G[(size_t)j * C_IN + i];
    }
}

// ---------------- K2-fallback: gram from fp32 with in-kernel cvt ----------------
__device__ inline short8 load_frag_f32(const float* p) {
    float4 a = *(const float4*)p;
    float4 b = *(const float4*)(p + 4);
    union { short8 s; __hip_bfloat162 h[4]; } u;
    u.h[0] = __float22bfloat162_rn(make_float2(a.x, a.y));
    u.h[1] = __float22bfloat162_rn(make_float2(a.z, a.w));
    u.h[2] = __float22bfloat162_rn(make_float2(b.x, b.y));
    u.h[3] = __float22bfloat162_rn(make_float2(b.z, b.w));
    return u.s;
}

__global__ __launch_bounds__(256)
void kgram_f32(const float* __restrict__ x, float* __restrict__ G) {
    int bz  = blockIdx.z;
    int n   = bz >> 2;
    int hw0 = (bz & 3) * 4096;
    int wave = threadIdx.x >> 6;
    int lane = threadIdx.x & 63;
    int wi = wave >> 1, wj = wave & 1;
    int I0 = blockIdx.x * 128 + wi * 64;
    int J0 = blockIdx.y * 128 + wj * 64;
    int m    = lane & 15;
    int koff = (lane >> 4) * 8;

    const float* baseA[4];
    const float* baseB[4];
#pragma unroll
    for (int t = 0; t < 4; ++t) {
        baseA[t] = x + ((size_t)n * C_IN + (I0 + t * 16 + m)) * HW + hw0 + koff;
        baseB[t] = x + ((size_t)n * C_IN + (J0 + t * 16 + m)) * HW + hw0 + koff;
    }

    f32x4 acc[4][4];
#pragma unroll
    for (int i = 0; i < 4; ++i)
#pragma unroll
        for (int j = 0; j < 4; ++j) acc[i][j] = {0.f, 0.f, 0.f, 0.f};

    for (int kk = 0; kk < 4096; kk += 32) {
        short8 afr[4], bfr[4];
#pragma unroll
        for (int t = 0; t < 4; ++t) {
            afr[t] = load_frag_f32(baseA[t] + kk);
            bfr[t] = load_frag_f32(baseB[t] + kk);
        }
#pragma unroll
        for (int i = 0; i < 4; ++i)
#pragma unroll
            for (int j = 0; j < 4; ++j)
                acc[i][j] = __builtin_amdgcn_mfma_f32_16x16x32_bf16(
                    afr[i], bfr[j], acc[i][j], 0, 0, 0);
    }

    int r0 = (lane >> 4) * 4;
    int cc = lane & 15;
#pragma unroll
    for (int i = 0; i < 4; ++i)
#pragma unroll
        for (int j = 0; j < 4; ++j)
#pragma unroll
            for (int r = 0; r < 4; ++r)
                atomicAdd(&G[(size_t)(I0 + i * 16 + r0 + r) * C_IN + (J0 + j * 16 + cc)],
                          acc[i][j][r]);
}

// ---------------- K3: BN stats + fold, 8 outputs per block ----------------
__global__ __launch_bounds__(256)
void kstats(const float* __restrict__ w1, const float* __restrict__ b1,
            const float* __restrict__ gamma, const float* __restrict__ beta,
            const float* __restrict__ s1, const float* __restrict__ G,
            float* __restrict__ w1p, float* __restrict__ b1p) {
    int o0 = blockIdx.x * OGRP;
    int tid = threadIdx.x;
    __shared__ float wr[OGRP][C_IN];          // 16 KB
    __shared__ float redd[4][OGRP];
    __shared__ float redq[4][OGRP];
    __shared__ float alpha_s[OGRP];

    for (int idx = tid; idx < OGRP * C_IN; idx += 256) {
        int og = idx >> 9, c = idx & (C_IN - 1);
        wr[og][c] = w1[(size_t)(o0 + og) * C_IN + c];
    }
    __syncthreads();

    float dot1[OGRP], quad[OGRP];
#pragma unroll
    for (int og = 0; og < OGRP; ++og) { dot1[og] = 0.f; quad[og] = 0.f; }

    for (int c = tid; c < C_IN; c += 256) {
        const float* gr = G + (size_t)c * C_IN;
        float s1c = s1[c];
        float inner[OGRP];
#pragma unroll
        for (int og = 0; og < OGRP; ++og) inner[og] = 0.f;
        for (int d = 0; d < C_IN; d += 4) {
            float4 gv = *(const float4*)(gr + d);
#pragma unroll
            for (int og = 0; og < OGRP; ++og) {
                float4 wv = *(const float4*)(&wr[og][d]);
                inner[og] += gv.x * wv.x + gv.y * wv.y + gv.z * wv.z + gv.w * wv.w;
            }
        }
#pragma unroll
        for (int og = 0; og < OGRP; ++og) {
            float wc = wr[og][c];
            quad[og] += inner[og] * wc;
            dot1[og] += s1c * wc;
        }
    }
#pragma unroll
    for (int og = 0; og < OGRP; ++og) {
        for (int off = 32; off; off >>= 1) {
            dot1[og] += __shfl_down(dot1[og], off, 64);
            quad[og] += __shfl_down(quad[og], off, 64);
        }
    }
    int lane = tid & 63, wv = tid >> 6;
    if (lane == 0) {
#pragma unroll
        for (int og = 0; og < OGRP; ++og) { redd[wv][og] = dot1[og]; redq[wv][og] = quad[og]; }
    }
    __syncthreads();
    if (tid < OGRP) {
        int og = tid;
        float d1 = redd[0][og] + redd[1][og] + redd[2][og] + redd[3][og];
        float q  = redq[0][og] + redq[1][og] + redq[2][og] + redq[3][og];
        float b  = b1[o0 + og];
        float mean = d1 / (float)PTOT + b;
        float eh2  = (q + 2.f * b * d1) / (float)PTOT + b * b;
        float var  = eh2 - mean * mean;
        float al   = gamma[o0 + og] * rsqrtf(var + BN_EPS);
        alpha_s[og] = al;
        b1p[o0 + og] = beta[o0 + og] + al * (b - mean);
    }
    __syncthreads();
    for (int idx = tid; idx < OGRP * C_IN; idx += 256) {
        int og = idx >> 9, c = idx & (C_IN - 1);
        w1p[(size_t)(o0 + og) * C_IN + c] = alpha_s[og] * wr[og][c];
    }
}

// ---------------- K4: features at sampled pixels ----------------
__global__ __launch_bounds__(256)
void kfeat(const float* __restrict__ x, const float* __restrict__ w1p,
           const float* __restrict__ b1p, const float* __restrict__ w2,
           const float* __restrict__ b2, const int* __restrict__ batch_idx,
           const int* __restrict__ pix_idx, float* __restrict__ cf,
           int M, int T, int n_view) {
    __shared__ float xcol[SPB][C_IN];
    __shared__ float h1[SPB][C_IN];
    __shared__ float fl[SPB][C_OUT];
    int tid = threadIdx.x;
    int m0 = blockIdx.x * SPB;

    for (int idx = tid; idx < SPB * C_IN; idx += 256) {
        int s = idx >> 9, c = idx & (C_IN - 1);
        int mm = m0 + s;
        float v = 0.f;
        if (mm < M) {
            int t = mm % T, vv = mm / T;          // cf row m = v*T + t
            int n = batch_idx[t];
            int pix = pix_idx[t * n_view + vv];
            v = x[((size_t)n * C_IN + c) * HW + pix];
        }
        xcol[s][c] = v;
    }
    __syncthreads();

    for (int o = tid; o < C_IN; o += 256) {
        float acc[SPB];
        float bb = b1p[o];
#pragma unroll
        for (int s = 0; s < SPB; ++s) acc[s] = bb;
        const float* wrp = w1p + (size_t)o * C_IN;
        for (int c = 0; c < C_IN; ++c) {
            float w = wrp[c];
#pragma unroll
            for (int s = 0; s < SPB; ++s) acc[s] += w * xcol[s][c];
        }
#pragma unroll
        for (int s = 0; s < SPB; ++s) h1[s][o] = fmaxf(acc[s], 0.f);
    }
    __syncthreads();

    {
        int j = tid;
        float acc[SPB];
        float bb = b2[j];
#pragma unroll
        for (int s = 0; s < SPB; ++s) acc[s] = bb;
        const float* wrp = w2 + (size_t)j * C_IN;
        for (int o = 0; o < C_IN; ++o) {
            float w = wrp[o];
#pragma unroll
            for (int s = 0; s < SPB; ++s) acc[s] += w * h1[s][o];
        }
#pragma unroll
        for (int s = 0; s < SPB; ++s) fl[s][j] = acc[s];
    }
    __syncthreads();

    int wv = tid >> 6, lane = tid & 63;
    {
        float sq = 0.f;
#pragma unroll
        for (int k = 0; k < 4; ++k) { float v = fl[wv][lane + 64 * k]; sq += v * v; }
        for (int off = 32; off; off >>= 1) sq += __shfl_down(sq, off, 64);
        float nrm = __shfl(sq, 0, 64);
        float rinv = 1.f / fmaxf(sqrtf(nrm), 1e-12f);
        int mm = m0 + wv;
        if (mm < M) {
#pragma unroll
            for (int k = 0; k < 4; ++k)
                cf[(size_t)mm * C_OUT + lane + 64 * k] = fl[wv][lane + 64 * k] * rinv;
        }
    }
}

// ---------------- K5: fused logits + loss, 8 anchor rows per block ----------------
__global__ __launch_bounds__(256)
void kloss(const float* __restrict__ cf, const int* __restrict__ y_cls,
           float* __restrict__ out, int M, int T) {
    int i0 = blockIdx.x * IGRP;
    int tid = threadIdx.x;
    __shared__ float ci[IGRP][C_OUT];         // 8 KB
    __shared__ float row[IGRP][MP];           // 32 KB
    __shared__ int   lbl[MP];                 // 4 KB
    __shared__ float redl[IGRP];
    int lane = tid & 63, wv = tid >> 6;

    for (int idx = tid; idx < IGRP * C_OUT; idx += 256) {
        int g = idx >> 8, c = idx & (C_OUT - 1);
        int ii = i0 + g;
        ci[g][c] = (ii < M) ? cf[(size_t)ii * C_OUT + c] : 0.f;
    }
    for (int j = tid; j < M; j += 256) lbl[j] = y_cls[j % T];
    __syncthreads();

    for (int j = tid; j < M; j += 256) {
        const float* cj = cf + (size_t)j * C_OUT;
        float acc[IGRP];
#pragma unroll
        for (int g = 0; g < IGRP; ++g) acc[g] = 0.f;
        for (int c = 0; c < C_OUT; c += 4) {
            float4 v = *(const float4*)(cj + c);
#pragma unroll
            for (int g = 0; g < IGRP; ++g) {
                float4 cv = *(const float4*)(&ci[g][c]);
                acc[g] += cv.x * v.x + cv.y * v.y + cv.z * v.z + cv.w * v.w;
            }
        }
#pragma unroll
        for (int g = 0; g < IGRP; ++g) row[g][j] = acc[g] * TEMP_INV;
    }
    __syncthreads();

    // wave wv handles anchors g = wv and g = wv + 4
    for (int g = wv; g < IGRP; g += 4) {
        int i = i0 + g;
        if (i < M) {
            int lbl_i = lbl[i];
            const float* r = row[g];

            float mx = -1e30f;
            for (int j = lane; j < M; j += 64) mx = fmaxf(mx, r[j]);
            for (int off = 32; off; off >>= 1) mx = fmaxf(mx, __shfl_down(mx, off, 64));
            mx = __shfl(mx, 0, 64);

            float neg = 0.f;
            for (int j = lane; j < M; j += 64)
                if (lbl[j] != lbl_i) neg += expf(r[j] - mx);
            for (int off = 32; off; off >>= 1) neg += __shfl_down(neg, off, 64);
            neg = __shfl(neg, 0, 64);

            float pos = 0.f; int cnt = 0;
            for (int j = lane; j < M; j += 64) {
                if (lbl[j] == lbl_i && j != i) {
                    float l = r[j] - mx;
                    pos += l - logf(expf(l) + neg);
                    cnt++;
                }
            }
            for (int off = 32; off; off >>= 1) {
                pos += __shfl_down(pos, off, 64);
                cnt += __shfl_down(cnt, off, 64);
            }
            if (lane == 0) redl[g] = -pos / ((float)cnt + 1e-6f);
        } else if (lane == 0) redl[g] = 0.f;
    }
    __syncthreads();
    if (tid == 0) {
        float s = 0.f;
        for (int g = 0; g < IGRP; ++g) s += redl[g];
        atomicAdd(out, s * (0.5f / (float)M));
    }
}

extern "C" void kernel_launch(void* const* d_in, const int* in_sizes, int n_in,
                              void* d_out, int out_size, void* d_ws, size_t ws_size,
                              hipStream_t stream) {
    const float* x     = (const float*)d_in[0];
    const float* w1    = (const float*)d_in[1];
    const float* b1    = (const float*)d_in[2];
    const float* gamma = (const float*)d_in[3];
    const float* beta  = (const float*)d_in[4];
    const float* w2    = (const float*)d_in[5];
    const float* b2    = (const float*)d_in[6];
    const int* batch_idx = (const int*)d_in[7];
    const int* pix_idx   = (const int*)d_in[8];
    const int* y_cls     = (const int*)d_in[9];

    int T = in_sizes[7];
    int M = in_sizes[8];
    int n_view = M / T;

    float* ws  = (float*)d_ws;
    float* s1  = ws + WS_S1;
    float* G   = ws + WS_G;
    float* w1p = ws + WS_W1P;
    float* b1p = ws + WS_B1P;
    float* cf  = ws + WS_CF;
    __hip_bfloat16* xb = (__hip_bfloat16*)(ws + WS_XB_F);

    hipMemsetAsync(s1, 0, (size_t)(C_IN + C_IN * C_IN) * sizeof(float), stream);
    hipMemsetAsync(d_out, 0, sizeof(float), stream);

    if (ws_size >= WS_NEED_FAST) {
        kprep<<<NIMG * C_IN, 256, 0, stream>>>(x, xb, s1);
        kgram_bf16<<<dim3(10, 128), 256, 0, stream>>>(xb, G);
        kmirror<<<C_IN, 256, 0, stream>>>(G);
    } else {
        ksum<<<NIMG * C_IN, 256, 0, stream>>>(x, s1);
        kgram_f32<<<dim3(4, 4, 32), 256, 0, stream>>>(x, G);
    }
    kstats<<<C_IN / OGRP, 256, 0, stream>>>(w1, b1, gamma, beta, s1, G, w1p, b1p);
    kfeat<<<(M + SPB - 1) / SPB, 256, 0, stream>>>(x, w1p, b1p, w2, b2,
                                                   batch_idx, pix_idx, cf, M, T, n_view);
    kloss<<<(M + IGRP - 1) / IGRP, 256, 0, stream>>>(cf, y_cls, (float*)d_out, M, T);
}

// Round 5
// 698.974 us; speedup vs baseline: 1.4994x; 1.0103x over previous
//
#include <hip/hip_runtime.h>
#include <hip/hip_bf16.h>

#define C_IN   512
#define C_OUT  256
#define HW     16384      // 128*128
#define NIMG   8
#define PTOT   (NIMG * HW)  // 131072
#define MP     1024
#define TEMP_INV (1.0f / 0.07f)
#define BN_EPS   1e-5f
#define SPB    4          // samples per block in feature kernel
#define OGRP   8          // outputs per block in kstats
#define IGRP   8          // anchor rows per block in kloss
#define BK     64         // K-chunk per LDS stage in kgram

typedef float  f32x4  __attribute__((ext_vector_type(4)));
typedef short  short8 __attribute__((ext_vector_type(8)));
typedef short  short4v __attribute__((ext_vector_type(4)));

// ws float layout
#define WS_S1   0
#define WS_G    (WS_S1 + C_IN)
#define WS_W1P  (WS_G + C_IN * C_IN)
#define WS_B1P  (WS_W1P + C_IN * C_IN)
#define WS_CF   (WS_B1P + C_IN)
#define WS_XB_F (WS_CF + MP * C_OUT)             // 787456 floats
#define WS_NEED_FAST ((size_t)WS_XB_F * 4 + (size_t)PTOT * C_IN * 2)

// ---------------- K0 (fast path): fused fp32->bf16 convert + channel sums ----------------
__global__ __launch_bounds__(256)
void kprep(const float* __restrict__ x, __hip_bfloat16* __restrict__ xb,
           float* __restrict__ s1) {
    int plane = blockIdx.x;           // n*512 + c
    int c = plane & (C_IN - 1);
    const float4* p = (const float4*)(x + (size_t)plane * HW);
    short4v* q = (short4v*)(xb + (size_t)plane * HW);
    float acc = 0.f;
    for (int i = threadIdx.x; i < HW / 4; i += 256) {
        float4 v = p[i];
        acc += v.x + v.y + v.z + v.w;
        union { short4v s; __hip_bfloat162 h[2]; } u;
        u.h[0] = __float22bfloat162_rn(make_float2(v.x, v.y));
        u.h[1] = __float22bfloat162_rn(make_float2(v.z, v.w));
        q[i] = u.s;
    }
    for (int off = 32; off; off >>= 1) acc += __shfl_down(acc, off, 64);
    __shared__ float red[4];
    int lane = threadIdx.x & 63, wv = threadIdx.x >> 6;
    if (lane == 0) red[wv] = acc;
    __syncthreads();
    if (threadIdx.x == 0)
        atomicAdd(&s1[c], red[0] + red[1] + red[2] + red[3]);
}

// ---------------- K1 (fallback): per-channel sums only ----------------
__global__ __launch_bounds__(256)
void ksum(const float* __restrict__ x, float* __restrict__ s1) {
    int plane = blockIdx.x;
    int c = plane & (C_IN - 1);
    const float4* p = (const float4*)(x + (size_t)plane * HW);
    float acc = 0.f;
    for (int i = threadIdx.x; i < HW / 4; i += 256) {
        float4 v = p[i];
        acc += v.x + v.y + v.z + v.w;
    }
    for (int off = 32; off; off >>= 1) acc += __shfl_down(acc, off, 64);
    __shared__ float red[4];
    int lane = threadIdx.x & 63, wv = threadIdx.x >> 6;
    if (lane == 0) red[wv] = acc;
    __syncthreads();
    if (threadIdx.x == 0)
        atomicAdd(&s1[c], red[0] + red[1] + red[2] + red[3]);
}

// ---------------- K2 (fast): LDS-staged gram, SINGLE-buffer m97-style 2-barrier loop ----------------
// 32 KB LDS + launch_bounds(256,4) -> 4 blocks/CU; cross-block overlap hides
// the vmcnt(0)+barrier drain (m97 lesson: concurrency beats explicit dbuf).
// LDS layout per panel: [row 0..127][slot 0..7], slot s of row r holds global
// k-quad (s ^ (r&7)); staged via global_load_lds width 16 (lane l -> row l>>3,
// slot l&7 => contiguous 128 B per row, conflict-free b128 fragment reads).
__device__ const int TILE_I[10] = {0,0,0,0,1,1,1,2,2,3};
__device__ const int TILE_J[10] = {0,1,2,3,1,2,3,2,3,3};

__global__ __launch_bounds__(256, 4)
void kgram_bf16(const __hip_bfloat16* __restrict__ xb, float* __restrict__ G) {
    __shared__ __hip_bfloat16 Abuf[128 * BK];   // 16 KB
    __shared__ __hip_bfloat16 Bbuf[128 * BK];   // 16 KB
    int tile  = blockIdx.x;
    int chunk = blockIdx.y;           // image n = chunk>>4, hw0 = (chunk&15)*1024
    int n   = chunk >> 4;
    int hw0 = (chunk & 15) * 1024;
    int wave = threadIdx.x >> 6;
    int lane = threadIdx.x & 63;
    int wi = wave >> 1, wj = wave & 1;
    int IT = TILE_I[tile] * 128;
    int JT = TILE_J[tile] * 128;

    const __hip_bfloat16* gA = xb + ((size_t)n * C_IN + IT) * HW + hw0;
    const __hip_bfloat16* gB = xb + ((size_t)n * C_IN + JT) * HW + hw0;

    int rrel = lane >> 3;             // 0..7
    int slot = lane & 7;

    f32x4 acc[4][4];
#pragma unroll
    for (int i = 0; i < 4; ++i)
#pragma unroll
        for (int j = 0; j < 4; ++j) acc[i][j] = {0.f, 0.f, 0.f, 0.f};

    int m  = lane & 15;
    int kq = lane >> 4;               // 0..3

#pragma unroll 1
    for (int s = 0; s < 16; ++s) {
        int kk = s * BK;
#pragma unroll
        for (int i_ = 0; i_ < 4; ++i_) {
            int row = wave * 32 + i_ * 8 + rrel;
            int g   = slot ^ (row & 7);
            __builtin_amdgcn_global_load_lds(
                (const __attribute__((address_space(1))) void*)
                    (gA + (size_t)row * HW + kk + g * 8),
                (__attribute__((address_space(3))) void*)
                    (&Abuf[(wave * 32 + i_ * 8) * BK]),
                16, 0, 0);
            __builtin_amdgcn_global_load_lds(
                (const __attribute__((address_space(1))) void*)
                    (gB + (size_t)row * HW + kk + g * 8),
                (__attribute__((address_space(3))) void*)
                    (&Bbuf[(wave * 32 + i_ * 8) * BK]),
                16, 0, 0);
        }
        __syncthreads();               // drains vmcnt -> LDS valid for all waves
#pragma unroll
        for (int h = 0; h < 2; ++h) {
            short8 af[4], bf[4];
#pragma unroll
            for (int t = 0; t < 4; ++t) {
                int ra = wi * 64 + t * 16 + m;
                int qa = (h * 4 + kq) ^ (ra & 7);
                af[t] = *(const short8*)&Abuf[ra * BK + qa * 8];
                int rb = wj * 64 + t * 16 + m;
                int qb = (h * 4 + kq) ^ (rb & 7);
                bf[t] = *(const short8*)&Bbuf[rb * BK + qb * 8];
            }
#pragma unroll
            for (int i_ = 0; i_ < 4; ++i_)
#pragma unroll
                for (int j_ = 0; j_ < 4; ++j_)
                    acc[i_][j_] = __builtin_amdgcn_mfma_f32_16x16x32_bf16(
                        af[i_], bf[j_], acc[i_][j_], 0, 0, 0);
        }
        __syncthreads();               // protect buffer reuse next stage
    }

    int r0 = (lane >> 4) * 4;
    int cc = lane & 15;
#pragma unroll
    for (int i = 0; i < 4; ++i)
#pragma unroll
        for (int j = 0; j < 4; ++j)
#pragma unroll
            for (int r = 0; r < 4; ++r)
                atomicAdd(&G[(size_t)(IT + wi * 64 + i * 16 + r0 + r) * C_IN
                             + (JT + wj * 64 + j * 16 + cc)],
                          acc[i][j][r]);
}

// ---------------- K2b: mirror upper triangle of G into lower ----------------
__global__ __launch_bounds__(256)
void kmirror(float* __restrict__ G) {
    int i = blockIdx.x;               // row
    for (int j = threadIdx.x; j < C_IN; j += 256) {
        if ((i >> 7) > (j >> 7))
            G[(size_t)i * C_IN + j] = G[(size_t)j * C_IN + i];
    }
}

// ---------------- K2-fallback: gram from fp32 with in-kernel cvt ----------------
__device__ inline short8 load_frag_f32(const float* p) {
    float4 a = *(const float4*)p;
    float4 b = *(const float4*)(p + 4);
    union { short8 s; __hip_bfloat162 h[4]; } u;
    u.h[0] = __float22bfloat162_rn(make_float2(a.x, a.y));
    u.h[1] = __float22bfloat162_rn(make_float2(a.z, a.w));
    u.h[2] = __float22bfloat162_rn(make_float2(b.x, b.y));
    u.h[3] = __float22bfloat162_rn(make_float2(b.z, b.w));
    return u.s;
}

__global__ __launch_bounds__(256)
void kgram_f32(const float* __restrict__ x, float* __restrict__ G) {
    int bz  = blockIdx.z;
    int n   = bz >> 2;
    int hw0 = (bz & 3) * 4096;
    int wave = threadIdx.x >> 6;
    int lane = threadIdx.x & 63;
    int wi = wave >> 1, wj = wave & 1;
    int I0 = blockIdx.x * 128 + wi * 64;
    int J0 = blockIdx.y * 128 + wj * 64;
    int m    = lane & 15;
    int koff = (lane >> 4) * 8;

    const float* baseA[4];
    const float* baseB[4];
#pragma unroll
    for (int t = 0; t < 4; ++t) {
        baseA[t] = x + ((size_t)n * C_IN + (I0 + t * 16 + m)) * HW + hw0 + koff;
        baseB[t] = x + ((size_t)n * C_IN + (J0 + t * 16 + m)) * HW + hw0 + koff;
    }

    f32x4 acc[4][4];
#pragma unroll
    for (int i = 0; i < 4; ++i)
#pragma unroll
        for (int j = 0; j < 4; ++j) acc[i][j] = {0.f, 0.f, 0.f, 0.f};

    for (int kk = 0; kk < 4096; kk += 32) {
        short8 afr[4], bfr[4];
#pragma unroll
        for (int t = 0; t < 4; ++t) {
            afr[t] = load_frag_f32(baseA[t] + kk);
            bfr[t] = load_frag_f32(baseB[t] + kk);
        }
#pragma unroll
        for (int i = 0; i < 4; ++i)
#pragma unroll
            for (int j = 0; j < 4; ++j)
                acc[i][j] = __builtin_amdgcn_mfma_f32_16x16x32_bf16(
                    afr[i], bfr[j], acc[i][j], 0, 0, 0);
    }

    int r0 = (lane >> 4) * 4;
    int cc = lane & 15;
#pragma unroll
    for (int i = 0; i < 4; ++i)
#pragma unroll
        for (int j = 0; j < 4; ++j)
#pragma unroll
            for (int r = 0; r < 4; ++r)
                atomicAdd(&G[(size_t)(I0 + i * 16 + r0 + r) * C_IN + (J0 + j * 16 + cc)],
                          acc[i][j][r]);
}

// ---------------- K3: BN stats + fold, 8 outputs per block ----------------
__global__ __launch_bounds__(256)
void kstats(const float* __restrict__ w1, const float* __restrict__ b1,
            const float* __restrict__ gamma, const float* __restrict__ beta,
            const float* __restrict__ s1, const float* __restrict__ G,
            float* __restrict__ w1p, float* __restrict__ b1p) {
    int o0 = blockIdx.x * OGRP;
    int tid = threadIdx.x;
    __shared__ float wr[OGRP][C_IN];          // 16 KB
    __shared__ float redd[4][OGRP];
    __shared__ float redq[4][OGRP];
    __shared__ float alpha_s[OGRP];

    for (int idx = tid; idx < OGRP * C_IN; idx += 256) {
        int og = idx >> 9, c = idx & (C_IN - 1);
        wr[og][c] = w1[(size_t)(o0 + og) * C_IN + c];
    }
    __syncthreads();

    float dot1[OGRP], quad[OGRP];
#pragma unroll
    for (int og = 0; og < OGRP; ++og) { dot1[og] = 0.f; quad[og] = 0.f; }

    for (int c = tid; c < C_IN; c += 256) {
        const float* gr = G + (size_t)c * C_IN;
        float s1c = s1[c];
        float inner[OGRP];
#pragma unroll
        for (int og = 0; og < OGRP; ++og) inner[og] = 0.f;
        for (int d = 0; d < C_IN; d += 4) {
            float4 gv = *(const float4*)(gr + d);
#pragma unroll
            for (int og = 0; og < OGRP; ++og) {
                float4 wv = *(const float4*)(&wr[og][d]);
                inner[og] += gv.x * wv.x + gv.y * wv.y + gv.z * wv.z + gv.w * wv.w;
            }
        }
#pragma unroll
        for (int og = 0; og < OGRP; ++og) {
            float wc = wr[og][c];
            quad[og] += inner[og] * wc;
            dot1[og] += s1c * wc;
        }
    }
#pragma unroll
    for (int og = 0; og < OGRP; ++og) {
        for (int off = 32; off; off >>= 1) {
            dot1[og] += __shfl_down(dot1[og], off, 64);
            quad[og] += __shfl_down(quad[og], off, 64);
        }
    }
    int lane = tid & 63, wv = tid >> 6;
    if (lane == 0) {
#pragma unroll
        for (int og = 0; og < OGRP; ++og) { redd[wv][og] = dot1[og]; redq[wv][og] = quad[og]; }
    }
    __syncthreads();
    if (tid < OGRP) {
        int og = tid;
        float d1 = redd[0][og] + redd[1][og] + redd[2][og] + redd[3][og];
        float q  = redq[0][og] + redq[1][og] + redq[2][og] + redq[3][og];
        float b  = b1[o0 + og];
        float mean = d1 / (float)PTOT + b;
        float eh2  = (q + 2.f * b * d1) / (float)PTOT + b * b;
        float var  = eh2 - mean * mean;
        float al   = gamma[o0 + og] * rsqrtf(var + BN_EPS);
        alpha_s[og] = al;
        b1p[o0 + og] = beta[o0 + og] + al * (b - mean);
    }
    __syncthreads();
    for (int idx = tid; idx < OGRP * C_IN; idx += 256) {
        int og = idx >> 9, c = idx & (C_IN - 1);
        w1p[(size_t)(o0 + og) * C_IN + c] = alpha_s[og] * wr[og][c];
    }
}

// ---------------- K4: features at sampled pixels (float4 weight reads) ----------------
__global__ __launch_bounds__(256)
void kfeat(const float* __restrict__ x, const float* __restrict__ w1p,
           const float* __restrict__ b1p, const float* __restrict__ w2,
           const float* __restrict__ b2, const int* __restrict__ batch_idx,
           const int* __restrict__ pix_idx, float* __restrict__ cf,
           int M, int T, int n_view) {
    __shared__ float xcol[SPB][C_IN];
    __shared__ float h1[SPB][C_IN];
    __shared__ float fl[SPB][C_OUT];
    int tid = threadIdx.x;
    int m0 = blockIdx.x * SPB;

    for (int idx = tid; idx < SPB * C_IN; idx += 256) {
        int s = idx >> 9, c = idx & (C_IN - 1);
        int mm = m0 + s;
        float v = 0.f;
        if (mm < M) {
            int t = mm % T, vv = mm / T;          // cf row m = v*T + t
            int n = batch_idx[t];
            int pix = pix_idx[t * n_view + vv];
            v = x[((size_t)n * C_IN + c) * HW + pix];
        }
        xcol[s][c] = v;
    }
    __syncthreads();

    for (int o = tid; o < C_IN; o += 256) {
        float acc[SPB];
        float bb = b1p[o];
#pragma unroll
        for (int s = 0; s < SPB; ++s) acc[s] = bb;
        const float* wrp = w1p + (size_t)o * C_IN;
        for (int c = 0; c < C_IN; c += 4) {
            float4 w = *(const float4*)(wrp + c);
#pragma unroll
            for (int s = 0; s < SPB; ++s) {
                float4 xv = *(const float4*)(&xcol[s][c]);
                acc[s] += w.x * xv.x + w.y * xv.y + w.z * xv.z + w.w * xv.w;
            }
        }
#pragma unroll
        for (int s = 0; s < SPB; ++s) h1[s][o] = fmaxf(acc[s], 0.f);
    }
    __syncthreads();

    {
        int j = tid;
        float acc[SPB];
        float bb = b2[j];
#pragma unroll
        for (int s = 0; s < SPB; ++s) acc[s] = bb;
        const float* wrp = w2 + (size_t)j * C_IN;
        for (int o = 0; o < C_IN; o += 4) {
            float4 w = *(const float4*)(wrp + o);
#pragma unroll
            for (int s = 0; s < SPB; ++s) {
                float4 hv = *(const float4*)(&h1[s][o]);
                acc[s] += w.x * hv.x + w.y * hv.y + w.z * hv.z + w.w * hv.w;
            }
        }
#pragma unroll
        for (int s = 0; s < SPB; ++s) fl[s][j] = acc[s];
    }
    __syncthreads();

    int wv = tid >> 6, lane = tid & 63;
    {
        float sq = 0.f;
#pragma unroll
        for (int k = 0; k < 4; ++k) { float v = fl[wv][lane + 64 * k]; sq += v * v; }
        for (int off = 32; off; off >>= 1) sq += __shfl_down(sq, off, 64);
        float nrm = __shfl(sq, 0, 64);
        float rinv = 1.f / fmaxf(sqrtf(nrm), 1e-12f);
        int mm = m0 + wv;
        if (mm < M) {
#pragma unroll
            for (int k = 0; k < 4; ++k)
                cf[(size_t)mm * C_OUT + lane + 64 * k] = fl[wv][lane + 64 * k] * rinv;
        }
    }
}

// ---------------- K5: fused logits + loss, 8 anchor rows per block ----------------
__global__ __launch_bounds__(256)
void kloss(const float* __restrict__ cf, const int* __restrict__ y_cls,
           float* __restrict__ out, int M, int T) {
    int i0 = blockIdx.x * IGRP;
    int tid = threadIdx.x;
    __shared__ float ci[IGRP][C_OUT];         // 8 KB
    __shared__ float row[IGRP][MP];           // 32 KB
    __shared__ int   lbl[MP];                 // 4 KB
    __shared__ float redl[IGRP];
    int lane = tid & 63, wv = tid >> 6;

    for (int idx = tid; idx < IGRP * C_OUT; idx += 256) {
        int g = idx >> 8, c = idx & (C_OUT - 1);
        int ii = i0 + g;
        ci[g][c] = (ii < M) ? cf[(size_t)ii * C_OUT + c] : 0.f;
    }
    for (int j = tid; j < M; j += 256) lbl[j] = y_cls[j % T];
    __syncthreads();

    for (int j = tid; j < M; j += 256) {
        const float* cj = cf + (size_t)j * C_OUT;
        float acc[IGRP];
#pragma unroll
        for (int g = 0; g < IGRP; ++g) acc[g] = 0.f;
        for (int c = 0; c < C_OUT; c += 4) {
            float4 v = *(const float4*)(cj + c);
#pragma unroll
            for (int g = 0; g < IGRP; ++g) {
                float4 cv = *(const float4*)(&ci[g][c]);
                acc[g] += cv.x * v.x + cv.y * v.y + cv.z * v.z + cv.w * v.w;
            }
        }
#pragma unroll
        for (int g = 0; g < IGRP; ++g) row[g][j] = acc[g] * TEMP_INV;
    }
    __syncthreads();

    for (int g = wv; g < IGRP; g += 4) {
        int i = i0 + g;
        if (i < M) {
            int lbl_i = lbl[i];
            const float* r = row[g];

            float mx = -1e30f;
            for (int j = lane; j < M; j += 64) mx = fmaxf(mx, r[j]);
            for (int off = 32; off; off >>= 1) mx = fmaxf(mx, __shfl_down(mx, off, 64));
            mx = __shfl(mx, 0, 64);

            float neg = 0.f;
            for (int j = lane; j < M; j += 64)
                if (lbl[j] != lbl_i) neg += expf(r[j] - mx);
            for (int off = 32; off; off >>= 1) neg += __shfl_down(neg, off, 64);
            neg = __shfl(neg, 0, 64);

            float pos = 0.f; int cnt = 0;
            for (int j = lane; j < M; j += 64) {
                if (lbl[j] == lbl_i && j != i) {
                    float l = r[j] - mx;
                    pos += l - logf(expf(l) + neg);
                    cnt++;
                }
            }
            for (int off = 32; off; off >>= 1) {
                pos += __shfl_down(pos, off, 64);
                cnt += __shfl_down(cnt, off, 64);
            }
            if (lane == 0) redl[g] = -pos / ((float)cnt + 1e-6f);
        } else if (lane == 0) redl[g] = 0.f;
    }
    __syncthreads();
    if (tid == 0) {
        float s = 0.f;
        for (int g = 0; g < IGRP; ++g) s += redl[g];
        atomicAdd(out, s * (0.5f / (float)M));
    }
}

extern "C" void kernel_launch(void* const* d_in, const int* in_sizes, int n_in,
                              void* d_out, int out_size, void* d_ws, size_t ws_size,
                              hipStream_t stream) {
    const float* x     = (const float*)d_in[0];
    const float* w1    = (const float*)d_in[1];
    const float* b1    = (const float*)d_in[2];
    const float* gamma = (const float*)d_in[3];
    const float* beta  = (const float*)d_in[4];
    const float* w2    = (const float*)d_in[5];
    const float* b2    = (const float*)d_in[6];
    const int* batch_idx = (const int*)d_in[7];
    const int* pix_idx   = (const int*)d_in[8];
    const int* y_cls     = (const int*)d_in[9];

    int T = in_sizes[7];
    int M = in_sizes[8];
    int n_view = M / T;

    float* ws  = (float*)d_ws;
    float* s1  = ws + WS_S1;
    float* G   = ws + WS_G;
    float* w1p = ws + WS_W1P;
    float* b1p = ws + WS_B1P;
    float* cf  = ws + WS_CF;
    __hip_bfloat16* xb = (__hip_bfloat16*)(ws + WS_XB_F);

    hipMemsetAsync(s1, 0, (size_t)(C_IN + C_IN * C_IN) * sizeof(float), stream);
    hipMemsetAsync(d_out, 0, sizeof(float), stream);

    if (ws_size >= WS_NEED_FAST) {
        kprep<<<NIMG * C_IN, 256, 0, stream>>>(x, xb, s1);
        kgram_bf16<<<dim3(10, 128), 256, 0, stream>>>(xb, G);
        kmirror<<<C_IN, 256, 0, stream>>>(G);
    } else {
        ksum<<<NIMG * C_IN, 256, 0, stream>>>(x, s1);
        kgram_f32<<<dim3(4, 4, 32), 256, 0, stream>>>(x, G);
    }
    kstats<<<C_IN / OGRP, 256, 0, stream>>>(w1, b1, gamma, beta, s1, G, w1p, b1p);
    kfeat<<<(M + SPB - 1) / SPB, 256, 0, stream>>>(x, w1p, b1p, w2, b2,
                                                   batch_idx, pix_idx, cf, M, T, n_view);
    kloss<<<(M + IGRP - 1) / IGRP, 256, 0, stream>>>(cf, y_cls, (float*)d_out, M, T);
}